// Round 4
// baseline (196.018 us; speedup 1.0000x reference)
//
#include <hip/hip_runtime.h>
#include <hip/hip_bf16.h>
#include <math.h>

#define B_  2
#define S_  2048
#define D_  1024
#define H_  16
#define DH_ 64
#define M_  (B_ * S_)   // 4096 tokens

typedef __attribute__((ext_vector_type(8))) short bf16x8;  // 8 bf16 (4 VGPRs)
typedef __attribute__((ext_vector_type(4))) float f32x4;   // MFMA C/D frag

__device__ __forceinline__ float fast_exp2(float x) {
  return __builtin_amdgcn_exp2f(x);   // v_exp_f32
}

__device__ __forceinline__ unsigned short f2bf(float f) {
  union { float f; unsigned u; } c; c.f = f;
  unsigned u = c.u;
  return (unsigned short)((u + 0x7FFFu + ((u >> 16) & 1u)) >> 16);  // RNE
}

// pack two floats -> one dword of 2 bf16 via HW cvt (1 VALU instr)
__device__ __forceinline__ unsigned cvtpk(float lo, float hi) {
  unsigned r;
  asm("v_cvt_pk_bf16_f32 %0, %1, %2" : "=v"(r) : "v"(lo), "v"(hi));
  return r;
}

__device__ __forceinline__ float logsig(float x) {
  // stable log_sigmoid; __logf ok: e in (0,1], result feeds bf16 anyway
  const float e = __expf(-fabsf(x));
  return fminf(x, 0.f) - __logf(1.f + e);
}

// ---------------------------------------------------------------------------
// Kernel 0: transpose Wq/Wk (fp32 [K][N]) -> bf16 W^T [N][K]
// ---------------------------------------------------------------------------
__global__ __launch_bounds__(256) void prep_w(
    const float* __restrict__ Wq, const float* __restrict__ Wk,
    unsigned short* __restrict__ WqT, unsigned short* __restrict__ WkT)
{
  __shared__ unsigned short T[64][72];
  const int tid = threadIdx.x;
  const int k0 = blockIdx.x * 64;
  const int n0 = blockIdx.y * 64;
  const float* W = blockIdx.z ? Wk : Wq;
  unsigned short* WT = blockIdx.z ? WkT : WqT;

  const int kr = tid >> 2, nc = (tid & 3) * 16;
  #pragma unroll
  for (int i = 0; i < 4; i++) {
    const float4 v = *(const float4*)&W[(size_t)(k0 + kr) * D_ + n0 + nc + i * 4];
    T[nc + i * 4 + 0][kr] = f2bf(v.x);
    T[nc + i * 4 + 1][kr] = f2bf(v.y);
    T[nc + i * 4 + 2][kr] = f2bf(v.z);
    T[nc + i * 4 + 3][kr] = f2bf(v.w);
  }
  __syncthreads();
  const int nr = tid >> 2, kc = (tid & 3) * 16;
  const uint4 a = *(const uint4*)&T[nr][kc];
  const uint4 b = *(const uint4*)&T[nr][kc + 8];
  *(uint4*)&WT[(size_t)(n0 + nr) * D_ + k0 + kc] = a;
  *(uint4*)&WT[(size_t)(n0 + nr) * D_ + k0 + kc + 8] = b;
}

// ---------------------------------------------------------------------------
// Kernel 1: Q = hs@Wq+bq ; K2 = logsig(logsig(Q)+Q+hs@Wk+bk)
//   A-operand is read DIRECTLY from fp32 hs (prep_hs fused away): the
//   prefetched float4s are converted via v_cvt_pk_bf16_f32 at ds_write time.
//   outputs K2b [M][D] (bf16), QT [H*64][M] (bf16).
// Tile 128m x 64n (n-block == one head), BK=64, 4 waves x 2 m-subtiles.
// T14 issue-early/write-late staging (verified round 3).
// ---------------------------------------------------------------------------
__global__ __launch_bounds__(256) void proj_kernel(
    const float* __restrict__ hs,
    const unsigned short* __restrict__ WqT, const unsigned short* __restrict__ WkT,
    const float* __restrict__ bqv, const float* __restrict__ bkv,
    unsigned short* __restrict__ K2b, unsigned short* __restrict__ QT)
{
  __shared__ unsigned short Ash[128][72];     // hs tile [m][k] (bf16)
  __shared__ unsigned short Bsh[2][64][72];   // W^T tiles [n][k]

  const int tid  = threadIdx.x;
  const int w    = tid >> 6;
  const int lane = tid & 63;
  const int quad = lane >> 4;
  const int l16  = lane & 15;
  const int m0 = blockIdx.x * 128;
  const int n0 = blockIdx.y * 64;     // = head * 64

  float bqs[4], bks[4];
  #pragma unroll
  for (int nt = 0; nt < 4; nt++) {
    bqs[nt] = bqv[n0 + nt * 16 + l16];
    bks[nt] = bkv[n0 + nt * 16 + l16];
  }

  f32x4 accQ[2][4], accK[2][4];
  #pragma unroll
  for (int st = 0; st < 2; st++)
    #pragma unroll
    for (int nt = 0; nt < 4; nt++) {
      accQ[st][nt] = (f32x4){0.f, 0.f, 0.f, 0.f};
      accK[st][nt] = (f32x4){0.f, 0.f, 0.f, 0.f};
    }

  const int am = tid >> 1, ac = (tid & 1) * 32;   // A: 128 rows x 64 cols (fp32 src)
  const int bn = tid >> 2, bc = (tid & 3) * 16;   // B: 64 rows x 64 cols per mat

  // ---- preload K-tile 0 into registers (T14 issue-early) ----
  float4 Af[8];
  uint4 BqA, BqB, BkA, BkB;
  {
    const size_t ra = (size_t)(m0 + am) * D_ + ac;
    #pragma unroll
    for (int i = 0; i < 8; i++) Af[i] = *(const float4*)&hs[ra + i * 4];
    const size_t rb = (size_t)(n0 + bn) * D_ + bc;
    BqA = *(const uint4*)&WqT[rb];  BqB = *(const uint4*)&WqT[rb + 8];
    BkA = *(const uint4*)&WkT[rb];  BkB = *(const uint4*)&WkT[rb + 8];
  }

  for (int k0 = 0; k0 < D_; k0 += 64) {
    if (k0) __syncthreads();   // all waves done reading the previous tile
    // stage tile k0 from registers; fp32 A converted to bf16 here
    #pragma unroll
    for (int i = 0; i < 4; i++) {
      uint4 t;
      t.x = cvtpk(Af[2 * i].x,     Af[2 * i].y);
      t.y = cvtpk(Af[2 * i].z,     Af[2 * i].w);
      t.z = cvtpk(Af[2 * i + 1].x, Af[2 * i + 1].y);
      t.w = cvtpk(Af[2 * i + 1].z, Af[2 * i + 1].w);
      *(uint4*)&Ash[am][ac + i * 8] = t;
    }
    *(uint4*)&Bsh[0][bn][bc]     = BqA;
    *(uint4*)&Bsh[0][bn][bc + 8] = BqB;
    *(uint4*)&Bsh[1][bn][bc]     = BkA;
    *(uint4*)&Bsh[1][bn][bc + 8] = BkB;
    __syncthreads();           // staged

    // issue tile k0+64's global loads NOW; they drain during compute
    if (k0 + 64 < D_) {
      const size_t ra = (size_t)(m0 + am) * D_ + (k0 + 64) + ac;
      #pragma unroll
      for (int i = 0; i < 8; i++) Af[i] = *(const float4*)&hs[ra + i * 4];
      const size_t rb = (size_t)(n0 + bn) * D_ + (k0 + 64) + bc;
      BqA = *(const uint4*)&WqT[rb];  BqB = *(const uint4*)&WqT[rb + 8];
      BkA = *(const uint4*)&WkT[rb];  BkB = *(const uint4*)&WkT[rb + 8];
    }

    #pragma unroll
    for (int kk = 0; kk < 2; kk++) {
      bf16x8 af[2];
      af[0] = *(const bf16x8*)&Ash[w * 32 + l16][kk * 32 + quad * 8];
      af[1] = *(const bf16x8*)&Ash[w * 32 + 16 + l16][kk * 32 + quad * 8];
      #pragma unroll
      for (int nt = 0; nt < 4; nt++) {
        const bf16x8 bq = *(const bf16x8*)&Bsh[0][nt * 16 + l16][kk * 32 + quad * 8];
        const bf16x8 bk = *(const bf16x8*)&Bsh[1][nt * 16 + l16][kk * 32 + quad * 8];
        accQ[0][nt] = __builtin_amdgcn_mfma_f32_16x16x32_bf16(af[0], bq, accQ[0][nt], 0, 0, 0);
        accQ[1][nt] = __builtin_amdgcn_mfma_f32_16x16x32_bf16(af[1], bq, accQ[1][nt], 0, 0, 0);
        accK[0][nt] = __builtin_amdgcn_mfma_f32_16x16x32_bf16(af[0], bk, accK[0][nt], 0, 0, 0);
        accK[1][nt] = __builtin_amdgcn_mfma_f32_16x16x32_bf16(af[1], bk, accK[1][nt], 0, 0, 0);
      }
    }
  }
  __syncthreads();   // protect epilogue's reuse of Bsh as Qt

  // epilogue: bias + logsigmoid chain; K2 row-major stores; Q -> LDS transpose
  unsigned short* Qt = &Bsh[0][0][0];   // 64*136 = 8704 shorts <= 9216 avail
  #pragma unroll
  for (int st = 0; st < 2; st++) {
    #pragma unroll
    for (int nt = 0; nt < 4; nt++) {
      float qv[4];
      #pragma unroll
      for (int r = 0; r < 4; r++) {
        const float q  = accQ[st][nt][r] + bqs[nt];
        const float kr = accK[st][nt][r] + bks[nt];
        const float k2 = logsig(logsig(q) + q + kr);
        const int m = m0 + w * 32 + st * 16 + quad * 4 + r;
        K2b[(size_t)m * D_ + n0 + nt * 16 + l16] = f2bf(k2);
        qv[r] = q;
      }
      const ushort4 qu = {f2bf(qv[0]), f2bf(qv[1]), f2bf(qv[2]), f2bf(qv[3])};
      *(ushort4*)&Qt[(nt * 16 + l16) * 136 + w * 32 + st * 16 + quad * 4] = qu;
    }
  }
  __syncthreads();
  {
    const int dr = tid >> 2, mc = (tid & 3) * 32;
    #pragma unroll
    for (int i = 0; i < 4; i++) {
      const uint4 v = *(const uint4*)&Qt[dr * 136 + mc + i * 8];
      *(uint4*)&QT[(size_t)(n0 + dr) * M_ + m0 + mc + i * 8] = v;
    }
  }
}

// ---------------------------------------------------------------------------
// Kernel 2: flash attention, S^T formulation, FIXED-SHIFT softmax.
//   s2 = c2 * sc (exp2 domain); p = exp2(s2 - 12). Shift-invariance makes a
//   constant shift exact; no max-reduce, no rescale.
// Round-4: QBLK 128 -> 64 for OCCUPANCY. Grid doubles to 1024 blocks; LDS
// 46 -> 36.9 KB -> 4 blocks/CU (16 waves/CU, was 8). Each wave owns ONE
// 16-q subtile (st loop removed). Sync structure, T14 reg prefetch, Qa
// write swizzle, cvtpk, setprio all unchanged from the verified r2 kernel.
// Block: 64 q x one (b,h); 4 waves x 1 subtile of 16 q; 64-key tiles.
// ---------------------------------------------------------------------------
__global__ __launch_bounds__(256) void attn_kernel(
    const unsigned short* __restrict__ QT,
    const unsigned short* __restrict__ K2b,
    const int* __restrict__ mask,
    float* __restrict__ out)
{
  __shared__ unsigned short Qa [64][72];   // Q [q][d], col-swizzled
  __shared__ unsigned short K2s[64][72];   // K2 [key][d]
  __shared__ unsigned short Vt [64][72];   // V^T [d][key]
  __shared__ unsigned short Psh[4][16][72];// per-wave P [q16][key64]

  const int tid  = threadIdx.x;
  const int w    = tid >> 6;
  const int lane = tid & 63;
  const int quad = lane >> 4;
  const int l16  = lane & 15;

  const int qt = blockIdx.x;          // 0..31
  const int bh = blockIdx.y;          // 0..31
  const int b = bh >> 4, h = bh & 15;
  const size_t qrow0 = (size_t)b * S_ + (size_t)qt * 64;
  const size_t krow0 = (size_t)b * S_;
  const size_t trow  = (size_t)h * 64;

  // ---- preload K/V tile 0 into registers (T14 issue-early) ----
  const int rr = tid >> 2, cc = (tid & 3) * 16;
  uint4 kreg0, kreg1, vreg0, vreg1;
  {
    const size_t kaddr = (krow0 + rr) * D_ + trow + cc;
    kreg0 = *(const uint4*)&K2b[kaddr];
    kreg1 = *(const uint4*)&K2b[kaddr + 8];
    const size_t vaddr = (trow + rr) * M_ + krow0 + cc;
    vreg0 = *(const uint4*)&QT[vaddr];
    vreg1 = *(const uint4*)&QT[vaddr + 8];
  }

  // ---- stage Qa [64 q][64 d] from QT (once per block), swizzled columns ----
  // thread: d-row dr = tid>>2, q-cols (tid&3)*16..+15; write col dr^((tid&3)<<3)
  // read side: wave w reads q rows w*16..w*16+15 -> un-XOR (w<<3) wave-uniform.
  {
    const int dr = tid >> 2, qc = (tid & 3) * 16;
    const int dcol = dr ^ ((tid & 3) << 3);
    #pragma unroll
    for (int i = 0; i < 2; i++) {
      const uint4 v = *(const uint4*)&QT[(trow + dr) * M_ + qrow0 + qc + i * 8];
      const unsigned short* p = (const unsigned short*)&v;
      #pragma unroll
      for (int j = 0; j < 8; j++) Qa[qc + i * 8 + j][dcol] = p[j];
    }
  }
  __syncthreads();

  // Q fragments (B-operand): read with wave-uniform un-swizzle XOR (free)
  bf16x8 qfrag[2];
  #pragma unroll
  for (int kk = 0; kk < 2; kk++)
    qfrag[kk] =
        *(const bf16x8*)&Qa[w * 16 + l16][(kk * 32 + quad * 8) ^ (w << 3)];

  // c2 = -(1/8)*log2(e)*msk ; fixed shift of 12 in exp2 domain
  const float c2 = (mask[qrow0 + w * 16 + l16] != 0) ? -0.18033688f : 0.f;
  float rl = 0.f;

  f32x4 Ot[4];
  #pragma unroll
  for (int dt = 0; dt < 4; dt++) Ot[dt] = (f32x4){0.f, 0.f, 0.f, 0.f};

  for (int kt = 0; kt < S_ / 64; kt++) {
    __syncthreads();   // all waves done reading LDS of tile kt-1
    // stage tile kt from registers (vmcnt wait auto-inserted for the loads)
    *(uint4*)&K2s[rr][cc]     = kreg0;
    *(uint4*)&K2s[rr][cc + 8] = kreg1;
    *(uint4*)&Vt [rr][cc]     = vreg0;
    *(uint4*)&Vt [rr][cc + 8] = vreg1;
    __syncthreads();   // staged

    // T14: issue tile kt+1's global loads NOW; they drain during compute
    if (kt + 1 < S_ / 64) {
      const size_t kaddr = (krow0 + (kt + 1) * 64 + rr) * D_ + trow + cc;
      kreg0 = *(const uint4*)&K2b[kaddr];
      kreg1 = *(const uint4*)&K2b[kaddr + 8];
      const size_t vaddr = (trow + rr) * M_ + krow0 + (kt + 1) * 64 + cc;
      vreg0 = *(const uint4*)&QT[vaddr];
      vreg1 = *(const uint4*)&QT[vaddr + 8];
    }

    bf16x8 k2f[4][2], vf[4][2];
    #pragma unroll
    for (int nt = 0; nt < 4; nt++)
      #pragma unroll
      for (int kk = 0; kk < 2; kk++) {
        k2f[nt][kk] = *(const bf16x8*)&K2s[nt * 16 + l16][kk * 32 + quad * 8];
        vf[nt][kk]  = *(const bf16x8*)&Vt [nt * 16 + l16][kk * 32 + quad * 8];
      }

    f32x4 sc[4];
    #pragma unroll
    for (int nt = 0; nt < 4; nt++) sc[nt] = (f32x4){0.f, 0.f, 0.f, 0.f};
    __builtin_amdgcn_s_setprio(1);
    #pragma unroll
    for (int kk = 0; kk < 2; kk++)
      #pragma unroll
      for (int nt = 0; nt < 4; nt++)
        sc[nt] = __builtin_amdgcn_mfma_f32_16x16x32_bf16(k2f[nt][kk], qfrag[kk], sc[nt], 0, 0, 0);
    __builtin_amdgcn_s_setprio(0);

    // p = exp2(c2*sc - 12); accumulate row-sum; pack pairs -> Psh
    #pragma unroll
    for (int nt = 0; nt < 4; nt++) {
      float p0 = fast_exp2(fmaf(sc[nt][0], c2, -12.f));
      float p1 = fast_exp2(fmaf(sc[nt][1], c2, -12.f));
      float p2 = fast_exp2(fmaf(sc[nt][2], c2, -12.f));
      float p3 = fast_exp2(fmaf(sc[nt][3], c2, -12.f));
      rl += (p0 + p1) + (p2 + p3);
      const uint2 pk = {cvtpk(p0, p1), cvtpk(p2, p3)};
      *(uint2*)&Psh[w][l16][nt * 16 + quad * 4] = pk;
    }

    #pragma unroll
    for (int kk = 0; kk < 2; kk++) {
      const bf16x8 pf = *(const bf16x8*)&Psh[w][l16][kk * 32 + quad * 8];
      __builtin_amdgcn_s_setprio(1);
      #pragma unroll
      for (int dt = 0; dt < 4; dt++)
        Ot[dt] = __builtin_amdgcn_mfma_f32_16x16x32_bf16(vf[dt][kk], pf, Ot[dt], 0, 0, 0);
      __builtin_amdgcn_s_setprio(0);
    }
  }

  // final row-sum across quads, then write O / l
  {
    float li = rl;
    li += __shfl_xor(li, 16);
    li += __shfl_xor(li, 32);
    const float inv = 1.f / fmaxf(li, 1e-35f);
    const size_t orow = (qrow0 + w * 16 + l16) * D_ + trow;
    #pragma unroll
    for (int dt = 0; dt < 4; dt++) {
      const float4 o = {Ot[dt][0] * inv, Ot[dt][1] * inv,
                        Ot[dt][2] * inv, Ot[dt][3] * inv};
      *(float4*)&out[orow + dt * 16 + quad * 4] = o;
    }
  }
}

extern "C" void kernel_launch(void* const* d_in, const int* in_sizes, int n_in,
                              void* d_out, int out_size, void* d_ws, size_t ws_size,
                              hipStream_t stream) {
  const float* hs  = (const float*)d_in[0];
  const int*   msk = (const int*)d_in[1];
  const float* Wq  = (const float*)d_in[2];
  const float* bq  = (const float*)d_in[3];
  const float* Wk  = (const float*)d_in[4];
  const float* bk  = (const float*)d_in[5];
  float* out = (float*)d_out;

  unsigned short* QT  = (unsigned short*)d_ws;             // [H*64][M_]  8 MB
  unsigned short* K2b = QT  + (size_t)D_ * M_;             // [M_][D_]    8 MB
  unsigned short* WqT = K2b + (size_t)M_ * D_;             // [D_][D_]    2 MB
  unsigned short* WkT = WqT + (size_t)D_ * D_;             // [D_][D_]    2 MB

  prep_w<<<dim3(D_ / 64, D_ / 64, 2), 256, 0, stream>>>(Wq, Wk, WqT, WkT);
  proj_kernel<<<dim3(M_ / 128, D_ / 64), 256, 0, stream>>>(hs, WqT, WkT, bq, bk, K2b, QT);
  attn_kernel<<<dim3(S_ / 64, B_ * H_), 256, 0, stream>>>(QT, K2b, msk, out);
}

// Round 5
// 182.871 us; speedup vs baseline: 1.0719x; 1.0719x over previous
//
#include <hip/hip_runtime.h>
#include <hip/hip_bf16.h>
#include <math.h>

#define B_  2
#define S_  2048
#define D_  1024
#define H_  16
#define DH_ 64
#define M_  (B_ * S_)   // 4096 tokens

typedef __attribute__((ext_vector_type(8))) short bf16x8;  // 8 bf16 (4 VGPRs)
typedef __attribute__((ext_vector_type(4))) float f32x4;   // MFMA C/D frag

__device__ __forceinline__ float fast_exp2(float x) {
  return __builtin_amdgcn_exp2f(x);   // v_exp_f32
}

__device__ __forceinline__ unsigned short f2bf(float f) {
  union { float f; unsigned u; } c; c.f = f;
  unsigned u = c.u;
  return (unsigned short)((u + 0x7FFFu + ((u >> 16) & 1u)) >> 16);  // RNE
}

// pack two floats -> one dword of 2 bf16 via HW cvt (1 VALU instr)
__device__ __forceinline__ unsigned cvtpk(float lo, float hi) {
  unsigned r;
  asm("v_cvt_pk_bf16_f32 %0, %1, %2" : "=v"(r) : "v"(lo), "v"(hi));
  return r;
}

__device__ __forceinline__ float logsig(float x) {
  // stable log_sigmoid; __logf ok: e in (0,1], result feeds bf16 anyway
  const float e = __expf(-fabsf(x));
  return fminf(x, 0.f) - __logf(1.f + e);
}

// ---------------------------------------------------------------------------
// Kernel 0: transpose Wq/Wk (fp32 [K][N]) -> bf16 W^T [N][K]
// ---------------------------------------------------------------------------
__global__ __launch_bounds__(256) void prep_w(
    const float* __restrict__ Wq, const float* __restrict__ Wk,
    unsigned short* __restrict__ WqT, unsigned short* __restrict__ WkT)
{
  __shared__ unsigned short T[64][72];
  const int tid = threadIdx.x;
  const int k0 = blockIdx.x * 64;
  const int n0 = blockIdx.y * 64;
  const float* W = blockIdx.z ? Wk : Wq;
  unsigned short* WT = blockIdx.z ? WkT : WqT;

  const int kr = tid >> 2, nc = (tid & 3) * 16;
  #pragma unroll
  for (int i = 0; i < 4; i++) {
    const float4 v = *(const float4*)&W[(size_t)(k0 + kr) * D_ + n0 + nc + i * 4];
    T[nc + i * 4 + 0][kr] = f2bf(v.x);
    T[nc + i * 4 + 1][kr] = f2bf(v.y);
    T[nc + i * 4 + 2][kr] = f2bf(v.z);
    T[nc + i * 4 + 3][kr] = f2bf(v.w);
  }
  __syncthreads();
  const int nr = tid >> 2, kc = (tid & 3) * 16;
  const uint4 a = *(const uint4*)&T[nr][kc];
  const uint4 b = *(const uint4*)&T[nr][kc + 8];
  *(uint4*)&WT[(size_t)(n0 + nr) * D_ + k0 + kc] = a;
  *(uint4*)&WT[(size_t)(n0 + nr) * D_ + k0 + kc + 8] = b;
}

// ---------------------------------------------------------------------------
// Kernel 1: Q = hs@Wq+bq ; K2 = logsig(logsig(Q)+Q+hs@Wk+bk)
//   A-operand read DIRECTLY from fp32 hs (prep_hs fused); prefetched float4s
//   converted via v_cvt_pk_bf16_f32 at ds_write time. (verified round 4)
// Tile 128m x 64n, BK=64, 4 waves x 2 m-subtiles, T14 staging (verified r3).
// ---------------------------------------------------------------------------
__global__ __launch_bounds__(256) void proj_kernel(
    const float* __restrict__ hs,
    const unsigned short* __restrict__ WqT, const unsigned short* __restrict__ WkT,
    const float* __restrict__ bqv, const float* __restrict__ bkv,
    unsigned short* __restrict__ K2b, unsigned short* __restrict__ QT)
{
  __shared__ unsigned short Ash[128][72];     // hs tile [m][k] (bf16)
  __shared__ unsigned short Bsh[2][64][72];   // W^T tiles [n][k]

  const int tid  = threadIdx.x;
  const int w    = tid >> 6;
  const int lane = tid & 63;
  const int quad = lane >> 4;
  const int l16  = lane & 15;
  const int m0 = blockIdx.x * 128;
  const int n0 = blockIdx.y * 64;     // = head * 64

  float bqs[4], bks[4];
  #pragma unroll
  for (int nt = 0; nt < 4; nt++) {
    bqs[nt] = bqv[n0 + nt * 16 + l16];
    bks[nt] = bkv[n0 + nt * 16 + l16];
  }

  f32x4 accQ[2][4], accK[2][4];
  #pragma unroll
  for (int st = 0; st < 2; st++)
    #pragma unroll
    for (int nt = 0; nt < 4; nt++) {
      accQ[st][nt] = (f32x4){0.f, 0.f, 0.f, 0.f};
      accK[st][nt] = (f32x4){0.f, 0.f, 0.f, 0.f};
    }

  const int am = tid >> 1, ac = (tid & 1) * 32;   // A: 128 rows x 64 cols (fp32 src)
  const int bn = tid >> 2, bc = (tid & 3) * 16;   // B: 64 rows x 64 cols per mat

  // ---- preload K-tile 0 into registers (T14 issue-early) ----
  float4 Af[8];
  uint4 BqA, BqB, BkA, BkB;
  {
    const size_t ra = (size_t)(m0 + am) * D_ + ac;
    #pragma unroll
    for (int i = 0; i < 8; i++) Af[i] = *(const float4*)&hs[ra + i * 4];
    const size_t rb = (size_t)(n0 + bn) * D_ + bc;
    BqA = *(const uint4*)&WqT[rb];  BqB = *(const uint4*)&WqT[rb + 8];
    BkA = *(const uint4*)&WkT[rb];  BkB = *(const uint4*)&WkT[rb + 8];
  }

  for (int k0 = 0; k0 < D_; k0 += 64) {
    if (k0) __syncthreads();   // all waves done reading the previous tile
    // stage tile k0 from registers; fp32 A converted to bf16 here
    #pragma unroll
    for (int i = 0; i < 4; i++) {
      uint4 t;
      t.x = cvtpk(Af[2 * i].x,     Af[2 * i].y);
      t.y = cvtpk(Af[2 * i].z,     Af[2 * i].w);
      t.z = cvtpk(Af[2 * i + 1].x, Af[2 * i + 1].y);
      t.w = cvtpk(Af[2 * i + 1].z, Af[2 * i + 1].w);
      *(uint4*)&Ash[am][ac + i * 8] = t;
    }
    *(uint4*)&Bsh[0][bn][bc]     = BqA;
    *(uint4*)&Bsh[0][bn][bc + 8] = BqB;
    *(uint4*)&Bsh[1][bn][bc]     = BkA;
    *(uint4*)&Bsh[1][bn][bc + 8] = BkB;
    __syncthreads();           // staged

    // issue tile k0+64's global loads NOW; they drain during compute
    if (k0 + 64 < D_) {
      const size_t ra = (size_t)(m0 + am) * D_ + (k0 + 64) + ac;
      #pragma unroll
      for (int i = 0; i < 8; i++) Af[i] = *(const float4*)&hs[ra + i * 4];
      const size_t rb = (size_t)(n0 + bn) * D_ + (k0 + 64) + bc;
      BqA = *(const uint4*)&WqT[rb];  BqB = *(const uint4*)&WqT[rb + 8];
      BkA = *(const uint4*)&WkT[rb];  BkB = *(const uint4*)&WkT[rb + 8];
    }

    #pragma unroll
    for (int kk = 0; kk < 2; kk++) {
      bf16x8 af[2];
      af[0] = *(const bf16x8*)&Ash[w * 32 + l16][kk * 32 + quad * 8];
      af[1] = *(const bf16x8*)&Ash[w * 32 + 16 + l16][kk * 32 + quad * 8];
      #pragma unroll
      for (int nt = 0; nt < 4; nt++) {
        const bf16x8 bq = *(const bf16x8*)&Bsh[0][nt * 16 + l16][kk * 32 + quad * 8];
        const bf16x8 bk = *(const bf16x8*)&Bsh[1][nt * 16 + l16][kk * 32 + quad * 8];
        accQ[0][nt] = __builtin_amdgcn_mfma_f32_16x16x32_bf16(af[0], bq, accQ[0][nt], 0, 0, 0);
        accQ[1][nt] = __builtin_amdgcn_mfma_f32_16x16x32_bf16(af[1], bq, accQ[1][nt], 0, 0, 0);
        accK[0][nt] = __builtin_amdgcn_mfma_f32_16x16x32_bf16(af[0], bk, accK[0][nt], 0, 0, 0);
        accK[1][nt] = __builtin_amdgcn_mfma_f32_16x16x32_bf16(af[1], bk, accK[1][nt], 0, 0, 0);
      }
    }
  }
  __syncthreads();   // protect epilogue's reuse of Bsh as Qt

  // epilogue: bias + logsigmoid chain; K2 row-major stores; Q -> LDS transpose
  unsigned short* Qt = &Bsh[0][0][0];   // 64*136 = 8704 shorts <= 9216 avail
  #pragma unroll
  for (int st = 0; st < 2; st++) {
    #pragma unroll
    for (int nt = 0; nt < 4; nt++) {
      float qv[4];
      #pragma unroll
      for (int r = 0; r < 4; r++) {
        const float q  = accQ[st][nt][r] + bqs[nt];
        const float kr = accK[st][nt][r] + bks[nt];
        const float k2 = logsig(logsig(q) + q + kr);
        const int m = m0 + w * 32 + st * 16 + quad * 4 + r;
        K2b[(size_t)m * D_ + n0 + nt * 16 + l16] = f2bf(k2);
        qv[r] = q;
      }
      const ushort4 qu = {f2bf(qv[0]), f2bf(qv[1]), f2bf(qv[2]), f2bf(qv[3])};
      *(ushort4*)&Qt[(nt * 16 + l16) * 136 + w * 32 + st * 16 + quad * 4] = qu;
    }
  }
  __syncthreads();
  {
    const int dr = tid >> 2, mc = (tid & 3) * 32;
    #pragma unroll
    for (int i = 0; i < 4; i++) {
      const uint4 v = *(const uint4*)&Qt[dr * 136 + mc + i * 8];
      *(uint4*)&QT[(size_t)(n0 + dr) * M_ + m0 + mc + i * 8] = v;
    }
  }
}

// ---------------------------------------------------------------------------
// Kernel 2: flash attention, S^T formulation, FIXED-SHIFT softmax.
//   s2 = c2 * sc (exp2 domain); p = exp2(s2 - 12). Shift-invariance makes a
//   constant shift exact; no max-reduce, no rescale.
// Round-5: QBLK back to 128 (r4's 64 doubled staging:compute ratio and
// regressed). TLP raised instead via 512 THREADS / 8 WAVES per block: each
// wave owns one 16-q subtile (the verified st-slice code), block count stays
// 512 (2/CU) but waves/CU doubles to 16 (4/SIMD). Per-tile staging total
// unchanged, halved per thread. Sync structure (2 barriers/iter), T14 reg
// prefetch, Qa XOR swizzle (8 q-groups), cvtpk, setprio preserved.
// LDS: Qa 18K + K2s 9K + Vt 9K + Psh[8] 18K = 54 KB -> 2 blocks/CU.
// ---------------------------------------------------------------------------
__global__ __launch_bounds__(512) void attn_kernel(
    const unsigned short* __restrict__ QT,
    const unsigned short* __restrict__ K2b,
    const int* __restrict__ mask,
    float* __restrict__ out)
{
  __shared__ unsigned short Qa [128][72];  // Q [q][d], col-swizzled
  __shared__ unsigned short K2s[64][72];   // K2 [key][d]
  __shared__ unsigned short Vt [64][72];   // V^T [d][key]
  __shared__ unsigned short Psh[8][16][72];// per-wave P [q16][key64]

  const int tid  = threadIdx.x;
  const int w    = tid >> 6;          // 0..7
  const int lane = tid & 63;
  const int quad = lane >> 4;
  const int l16  = lane & 15;

  const int qt = blockIdx.x;          // 0..15
  const int bh = blockIdx.y;          // 0..31
  const int b = bh >> 4, h = bh & 15;
  const size_t qrow0 = (size_t)b * S_ + (size_t)qt * 128;
  const size_t krow0 = (size_t)b * S_;
  const size_t trow  = (size_t)h * 64;

  // ---- preload K/V tile 0 into registers (T14 issue-early) ----
  // 512 threads: one uint4 (8 shorts) per thread per matrix.
  const int rr = tid >> 3, cc = (tid & 7) * 8;
  uint4 kreg, vreg;
  {
    kreg = *(const uint4*)&K2b[(krow0 + rr) * D_ + trow + cc];
    vreg = *(const uint4*)&QT [(trow + rr) * M_ + krow0 + cc];
  }

  // ---- stage Qa [128 q][64 d] from QT (once per block), swizzled cols ----
  // thread: d-row dr = tid>>3, q-group qg = tid&7 (16 q each);
  // write col = dr ^ (qg<<3). Read side: wave w reads q rows w*16..+15 ->
  // un-XOR (w<<3), wave-uniform (free).
  {
    const int dr = tid >> 3, qg = tid & 7;
    const int qc = qg * 16;
    const int dcol = dr ^ (qg << 3);
    #pragma unroll
    for (int i = 0; i < 2; i++) {
      const uint4 v = *(const uint4*)&QT[(trow + dr) * M_ + qrow0 + qc + i * 8];
      const unsigned short* p = (const unsigned short*)&v;
      #pragma unroll
      for (int j = 0; j < 8; j++) Qa[qc + i * 8 + j][dcol] = p[j];
    }
  }
  __syncthreads();

  // Q fragments (B-operand): read with wave-uniform un-swizzle XOR (free)
  bf16x8 qfrag[2];
  #pragma unroll
  for (int kk = 0; kk < 2; kk++)
    qfrag[kk] =
        *(const bf16x8*)&Qa[w * 16 + l16][(kk * 32 + quad * 8) ^ (w << 3)];

  // c2 = -(1/8)*log2(e)*msk ; fixed shift of 12 in exp2 domain
  const float c2 = (mask[qrow0 + w * 16 + l16] != 0) ? -0.18033688f : 0.f;
  float rl = 0.f;

  f32x4 Ot[4];
  #pragma unroll
  for (int dt = 0; dt < 4; dt++) Ot[dt] = (f32x4){0.f, 0.f, 0.f, 0.f};

  for (int kt = 0; kt < S_ / 64; kt++) {
    __syncthreads();   // all waves done reading LDS of tile kt-1
    // stage tile kt from registers (vmcnt wait auto-inserted for the loads)
    *(uint4*)&K2s[rr][cc] = kreg;
    *(uint4*)&Vt [rr][cc] = vreg;
    __syncthreads();   // staged

    // T14: issue tile kt+1's global loads NOW; they drain during compute
    if (kt + 1 < S_ / 64) {
      kreg = *(const uint4*)&K2b[(krow0 + (kt + 1) * 64 + rr) * D_ + trow + cc];
      vreg = *(const uint4*)&QT [(trow + rr) * M_ + krow0 + (kt + 1) * 64 + cc];
    }

    bf16x8 k2f[4][2], vf[4][2];
    #pragma unroll
    for (int nt = 0; nt < 4; nt++)
      #pragma unroll
      for (int kk = 0; kk < 2; kk++) {
        k2f[nt][kk] = *(const bf16x8*)&K2s[nt * 16 + l16][kk * 32 + quad * 8];
        vf[nt][kk]  = *(const bf16x8*)&Vt [nt * 16 + l16][kk * 32 + quad * 8];
      }

    f32x4 sc[4];
    #pragma unroll
    for (int nt = 0; nt < 4; nt++) sc[nt] = (f32x4){0.f, 0.f, 0.f, 0.f};
    __builtin_amdgcn_s_setprio(1);
    #pragma unroll
    for (int kk = 0; kk < 2; kk++)
      #pragma unroll
      for (int nt = 0; nt < 4; nt++)
        sc[nt] = __builtin_amdgcn_mfma_f32_16x16x32_bf16(k2f[nt][kk], qfrag[kk], sc[nt], 0, 0, 0);
    __builtin_amdgcn_s_setprio(0);

    // p = exp2(c2*sc - 12); accumulate row-sum; pack pairs -> Psh
    #pragma unroll
    for (int nt = 0; nt < 4; nt++) {
      float p0 = fast_exp2(fmaf(sc[nt][0], c2, -12.f));
      float p1 = fast_exp2(fmaf(sc[nt][1], c2, -12.f));
      float p2 = fast_exp2(fmaf(sc[nt][2], c2, -12.f));
      float p3 = fast_exp2(fmaf(sc[nt][3], c2, -12.f));
      rl += (p0 + p1) + (p2 + p3);
      const uint2 pk = {cvtpk(p0, p1), cvtpk(p2, p3)};
      *(uint2*)&Psh[w][l16][nt * 16 + quad * 4] = pk;
    }

    #pragma unroll
    for (int kk = 0; kk < 2; kk++) {
      const bf16x8 pf = *(const bf16x8*)&Psh[w][l16][kk * 32 + quad * 8];
      __builtin_amdgcn_s_setprio(1);
      #pragma unroll
      for (int dt = 0; dt < 4; dt++)
        Ot[dt] = __builtin_amdgcn_mfma_f32_16x16x32_bf16(vf[dt][kk], pf, Ot[dt], 0, 0, 0);
      __builtin_amdgcn_s_setprio(0);
    }
  }

  // final row-sum across quads, then write O / l
  {
    float li = rl;
    li += __shfl_xor(li, 16);
    li += __shfl_xor(li, 32);
    const float inv = 1.f / fmaxf(li, 1e-35f);
    const size_t orow = (qrow0 + w * 16 + l16) * D_ + trow;
    #pragma unroll
    for (int dt = 0; dt < 4; dt++) {
      const float4 o = {Ot[dt][0] * inv, Ot[dt][1] * inv,
                        Ot[dt][2] * inv, Ot[dt][3] * inv};
      *(float4*)&out[orow + dt * 16 + quad * 4] = o;
    }
  }
}

extern "C" void kernel_launch(void* const* d_in, const int* in_sizes, int n_in,
                              void* d_out, int out_size, void* d_ws, size_t ws_size,
                              hipStream_t stream) {
  const float* hs  = (const float*)d_in[0];
  const int*   msk = (const int*)d_in[1];
  const float* Wq  = (const float*)d_in[2];
  const float* bq  = (const float*)d_in[3];
  const float* Wk  = (const float*)d_in[4];
  const float* bk  = (const float*)d_in[5];
  float* out = (float*)d_out;

  unsigned short* QT  = (unsigned short*)d_ws;             // [H*64][M_]  8 MB
  unsigned short* K2b = QT  + (size_t)D_ * M_;             // [M_][D_]    8 MB
  unsigned short* WqT = K2b + (size_t)M_ * D_;             // [D_][D_]    2 MB
  unsigned short* WkT = WqT + (size_t)D_ * D_;             // [D_][D_]    2 MB

  prep_w<<<dim3(D_ / 64, D_ / 64, 2), 256, 0, stream>>>(Wq, Wk, WqT, WkT);
  proj_kernel<<<dim3(M_ / 128, D_ / 64), 256, 0, stream>>>(hs, WqT, WkT, bq, bk, K2b, QT);
  attn_kernel<<<dim3(S_ / 128, B_ * H_), 512, 0, stream>>>(QT, K2b, msk, out);
}

// Round 6
// 182.017 us; speedup vs baseline: 1.0769x; 1.0047x over previous
//
#include <hip/hip_runtime.h>
#include <hip/hip_bf16.h>
#include <math.h>

#define B_  2
#define S_  2048
#define D_  1024
#define H_  16
#define DH_ 64
#define M_  (B_ * S_)   // 4096 tokens

typedef __attribute__((ext_vector_type(8))) short bf16x8;  // 8 bf16 (4 VGPRs)
typedef __attribute__((ext_vector_type(4))) float f32x4;   // MFMA C/D frag

__device__ __forceinline__ float fast_exp2(float x) {
  return __builtin_amdgcn_exp2f(x);   // v_exp_f32
}

__device__ __forceinline__ unsigned short f2bf(float f) {
  union { float f; unsigned u; } c; c.f = f;
  unsigned u = c.u;
  return (unsigned short)((u + 0x7FFFu + ((u >> 16) & 1u)) >> 16);  // RNE
}

// pack two floats -> one dword of 2 bf16 via HW cvt (1 VALU instr)
__device__ __forceinline__ unsigned cvtpk(float lo, float hi) {
  unsigned r;
  asm("v_cvt_pk_bf16_f32 %0, %1, %2" : "=v"(r) : "v"(lo), "v"(hi));
  return r;
}

__device__ __forceinline__ float logsig(float x) {
  // stable log_sigmoid; __logf ok: e in (0,1], result feeds bf16 anyway
  const float e = __expf(-fabsf(x));
  return fminf(x, 0.f) - __logf(1.f + e);
}

// ---------------------------------------------------------------------------
// Kernel 0: transpose Wq/Wk (fp32 [K][N]) -> bf16 W^T [N][K]
// ---------------------------------------------------------------------------
__global__ __launch_bounds__(256) void prep_w(
    const float* __restrict__ Wq, const float* __restrict__ Wk,
    unsigned short* __restrict__ WqT, unsigned short* __restrict__ WkT)
{
  __shared__ unsigned short T[64][72];
  const int tid = threadIdx.x;
  const int k0 = blockIdx.x * 64;
  const int n0 = blockIdx.y * 64;
  const float* W = blockIdx.z ? Wk : Wq;
  unsigned short* WT = blockIdx.z ? WkT : WqT;

  const int kr = tid >> 2, nc = (tid & 3) * 16;
  #pragma unroll
  for (int i = 0; i < 4; i++) {
    const float4 v = *(const float4*)&W[(size_t)(k0 + kr) * D_ + n0 + nc + i * 4];
    T[nc + i * 4 + 0][kr] = f2bf(v.x);
    T[nc + i * 4 + 1][kr] = f2bf(v.y);
    T[nc + i * 4 + 2][kr] = f2bf(v.z);
    T[nc + i * 4 + 3][kr] = f2bf(v.w);
  }
  __syncthreads();
  const int nr = tid >> 2, kc = (tid & 3) * 16;
  const uint4 a = *(const uint4*)&T[nr][kc];
  const uint4 b = *(const uint4*)&T[nr][kc + 8];
  *(uint4*)&WT[(size_t)(n0 + nr) * D_ + k0 + kc] = a;
  *(uint4*)&WT[(size_t)(n0 + nr) * D_ + k0 + kc + 8] = b;
}

// ---------------------------------------------------------------------------
// Kernel 1: Q = hs@Wq+bq ; K2 = logsig(logsig(Q)+Q+hs@Wk+bk)
//   A-operand read DIRECTLY from fp32 hs (prep_hs fused); prefetched float4s
//   converted via v_cvt_pk_bf16_f32 at ds_write time. (verified round 4)
// Tile 128m x 64n, BK=64, 4 waves x 2 m-subtiles, T14 staging (verified r3).
// ---------------------------------------------------------------------------
__global__ __launch_bounds__(256) void proj_kernel(
    const float* __restrict__ hs,
    const unsigned short* __restrict__ WqT, const unsigned short* __restrict__ WkT,
    const float* __restrict__ bqv, const float* __restrict__ bkv,
    unsigned short* __restrict__ K2b, unsigned short* __restrict__ QT)
{
  __shared__ unsigned short Ash[128][72];     // hs tile [m][k] (bf16)
  __shared__ unsigned short Bsh[2][64][72];   // W^T tiles [n][k]

  const int tid  = threadIdx.x;
  const int w    = tid >> 6;
  const int lane = tid & 63;
  const int quad = lane >> 4;
  const int l16  = lane & 15;
  const int m0 = blockIdx.x * 128;
  const int n0 = blockIdx.y * 64;     // = head * 64

  float bqs[4], bks[4];
  #pragma unroll
  for (int nt = 0; nt < 4; nt++) {
    bqs[nt] = bqv[n0 + nt * 16 + l16];
    bks[nt] = bkv[n0 + nt * 16 + l16];
  }

  f32x4 accQ[2][4], accK[2][4];
  #pragma unroll
  for (int st = 0; st < 2; st++)
    #pragma unroll
    for (int nt = 0; nt < 4; nt++) {
      accQ[st][nt] = (f32x4){0.f, 0.f, 0.f, 0.f};
      accK[st][nt] = (f32x4){0.f, 0.f, 0.f, 0.f};
    }

  const int am = tid >> 1, ac = (tid & 1) * 32;   // A: 128 rows x 64 cols (fp32 src)
  const int bn = tid >> 2, bc = (tid & 3) * 16;   // B: 64 rows x 64 cols per mat

  // ---- preload K-tile 0 into registers (T14 issue-early) ----
  float4 Af[8];
  uint4 BqA, BqB, BkA, BkB;
  {
    const size_t ra = (size_t)(m0 + am) * D_ + ac;
    #pragma unroll
    for (int i = 0; i < 8; i++) Af[i] = *(const float4*)&hs[ra + i * 4];
    const size_t rb = (size_t)(n0 + bn) * D_ + bc;
    BqA = *(const uint4*)&WqT[rb];  BqB = *(const uint4*)&WqT[rb + 8];
    BkA = *(const uint4*)&WkT[rb];  BkB = *(const uint4*)&WkT[rb + 8];
  }

  for (int k0 = 0; k0 < D_; k0 += 64) {
    if (k0) __syncthreads();   // all waves done reading the previous tile
    // stage tile k0 from registers; fp32 A converted to bf16 here
    #pragma unroll
    for (int i = 0; i < 4; i++) {
      uint4 t;
      t.x = cvtpk(Af[2 * i].x,     Af[2 * i].y);
      t.y = cvtpk(Af[2 * i].z,     Af[2 * i].w);
      t.z = cvtpk(Af[2 * i + 1].x, Af[2 * i + 1].y);
      t.w = cvtpk(Af[2 * i + 1].z, Af[2 * i + 1].w);
      *(uint4*)&Ash[am][ac + i * 8] = t;
    }
    *(uint4*)&Bsh[0][bn][bc]     = BqA;
    *(uint4*)&Bsh[0][bn][bc + 8] = BqB;
    *(uint4*)&Bsh[1][bn][bc]     = BkA;
    *(uint4*)&Bsh[1][bn][bc + 8] = BkB;
    __syncthreads();           // staged

    // issue tile k0+64's global loads NOW; they drain during compute
    if (k0 + 64 < D_) {
      const size_t ra = (size_t)(m0 + am) * D_ + (k0 + 64) + ac;
      #pragma unroll
      for (int i = 0; i < 8; i++) Af[i] = *(const float4*)&hs[ra + i * 4];
      const size_t rb = (size_t)(n0 + bn) * D_ + (k0 + 64) + bc;
      BqA = *(const uint4*)&WqT[rb];  BqB = *(const uint4*)&WqT[rb + 8];
      BkA = *(const uint4*)&WkT[rb];  BkB = *(const uint4*)&WkT[rb + 8];
    }

    #pragma unroll
    for (int kk = 0; kk < 2; kk++) {
      bf16x8 af[2];
      af[0] = *(const bf16x8*)&Ash[w * 32 + l16][kk * 32 + quad * 8];
      af[1] = *(const bf16x8*)&Ash[w * 32 + 16 + l16][kk * 32 + quad * 8];
      #pragma unroll
      for (int nt = 0; nt < 4; nt++) {
        const bf16x8 bq = *(const bf16x8*)&Bsh[0][nt * 16 + l16][kk * 32 + quad * 8];
        const bf16x8 bk = *(const bf16x8*)&Bsh[1][nt * 16 + l16][kk * 32 + quad * 8];
        accQ[0][nt] = __builtin_amdgcn_mfma_f32_16x16x32_bf16(af[0], bq, accQ[0][nt], 0, 0, 0);
        accQ[1][nt] = __builtin_amdgcn_mfma_f32_16x16x32_bf16(af[1], bq, accQ[1][nt], 0, 0, 0);
        accK[0][nt] = __builtin_amdgcn_mfma_f32_16x16x32_bf16(af[0], bk, accK[0][nt], 0, 0, 0);
        accK[1][nt] = __builtin_amdgcn_mfma_f32_16x16x32_bf16(af[1], bk, accK[1][nt], 0, 0, 0);
      }
    }
  }
  __syncthreads();   // protect epilogue's reuse of Bsh as Qt

  // epilogue: bias + logsigmoid chain; K2 row-major stores; Q -> LDS transpose
  unsigned short* Qt = &Bsh[0][0][0];   // 64*136 = 8704 shorts <= 9216 avail
  #pragma unroll
  for (int st = 0; st < 2; st++) {
    #pragma unroll
    for (int nt = 0; nt < 4; nt++) {
      float qv[4];
      #pragma unroll
      for (int r = 0; r < 4; r++) {
        const float q  = accQ[st][nt][r] + bqs[nt];
        const float kr = accK[st][nt][r] + bks[nt];
        const float k2 = logsig(logsig(q) + q + kr);
        const int m = m0 + w * 32 + st * 16 + quad * 4 + r;
        K2b[(size_t)m * D_ + n0 + nt * 16 + l16] = f2bf(k2);
        qv[r] = q;
      }
      const ushort4 qu = {f2bf(qv[0]), f2bf(qv[1]), f2bf(qv[2]), f2bf(qv[3])};
      *(ushort4*)&Qt[(nt * 16 + l16) * 136 + w * 32 + st * 16 + quad * 4] = qu;
    }
  }
  __syncthreads();
  {
    const int dr = tid >> 2, mc = (tid & 3) * 32;
    #pragma unroll
    for (int i = 0; i < 4; i++) {
      const uint4 v = *(const uint4*)&Qt[dr * 136 + mc + i * 8];
      *(uint4*)&QT[(size_t)(n0 + dr) * M_ + m0 + mc + i * 8] = v;
    }
  }
}

// ---------------------------------------------------------------------------
// Kernel 2: flash attention, S^T formulation, FIXED-SHIFT softmax.
//   s2 = c2 * sc (exp2 domain); p = exp2(s2 - 12). Shift-invariance makes a
//   constant shift exact; no max-reduce, no rescale.
// Round-6: CONSOLIDATE to 1 block/CU. QBLK 256, 1024 threads, 16 waves,
// each wave owns one 16-q subtile (verbatim per-wave code from verified r5).
// Per-CU LDS staging traffic, barrier count and K/V global fetch all HALVE
// (8 blocks per (b,h) instead of 16, no duplicate K/V streaming by 2
// co-resident blocks). Occupancy stays 16 waves/CU (4/SIMD) — the proven
// TLP level — while LDS-pipe load drops ~35%.
// LDS: Qa 36K + K2s 9K + Vt 9K + Psh[16] 36K = 90 KB -> 1 block/CU,
// grid = 8 x 32 = 256 blocks = exactly one per CU.
// ---------------------------------------------------------------------------
__global__ __launch_bounds__(1024) void attn_kernel(
    const unsigned short* __restrict__ QT,
    const unsigned short* __restrict__ K2b,
    const int* __restrict__ mask,
    float* __restrict__ out)
{
  __shared__ unsigned short Qa [256][72];   // Q [q][d], col-swizzled
  __shared__ unsigned short K2s[64][72];    // K2 [key][d]
  __shared__ unsigned short Vt [64][72];    // V^T [d][key]
  __shared__ unsigned short Psh[16][16][72];// per-wave P [q16][key64]

  const int tid  = threadIdx.x;
  const int w    = tid >> 6;          // 0..15
  const int lane = tid & 63;
  const int quad = lane >> 4;
  const int l16  = lane & 15;

  const int qt = blockIdx.x;          // 0..7
  const int bh = blockIdx.y;          // 0..31
  const int b = bh >> 4, h = bh & 15;
  const size_t qrow0 = (size_t)b * S_ + (size_t)qt * 256;
  const size_t krow0 = (size_t)b * S_;
  const size_t trow  = (size_t)h * 64;

  // ---- preload K/V tile 0 into registers (T14 issue-early) ----
  // 1024 threads: one uint2 (4 shorts) per thread per matrix.
  const int rr = tid >> 4, cc = (tid & 15) * 4;
  uint2 kreg, vreg;
  {
    kreg = *(const uint2*)&K2b[(krow0 + rr) * D_ + trow + cc];
    vreg = *(const uint2*)&QT [(trow + rr) * M_ + krow0 + cc];
  }

  // ---- stage Qa [256 q][64 d] from QT (once per block), swizzled cols ----
  // thread: d-row dr = tid>>4, q-group qg = tid&15 (16 q each);
  // write col = dr ^ ((qg&7)<<3). Read side: wave w reads q rows w*16..+15
  // -> un-XOR ((w&7)<<3), wave-uniform (free).
  {
    const int dr = tid >> 4, qg = tid & 15;
    const int qc = qg * 16;
    const int dcol = dr ^ ((qg & 7) << 3);
    #pragma unroll
    for (int i = 0; i < 2; i++) {
      const uint4 v = *(const uint4*)&QT[(trow + dr) * M_ + qrow0 + qc + i * 8];
      const unsigned short* p = (const unsigned short*)&v;
      #pragma unroll
      for (int j = 0; j < 8; j++) Qa[qc + i * 8 + j][dcol] = p[j];
    }
  }
  __syncthreads();

  // Q fragments (B-operand): read with wave-uniform un-swizzle XOR (free)
  bf16x8 qfrag[2];
  #pragma unroll
  for (int kk = 0; kk < 2; kk++)
    qfrag[kk] =
        *(const bf16x8*)&Qa[w * 16 + l16][(kk * 32 + quad * 8) ^ ((w & 7) << 3)];

  // c2 = -(1/8)*log2(e)*msk ; fixed shift of 12 in exp2 domain
  const float c2 = (mask[qrow0 + w * 16 + l16] != 0) ? -0.18033688f : 0.f;
  float rl = 0.f;

  f32x4 Ot[4];
  #pragma unroll
  for (int dt = 0; dt < 4; dt++) Ot[dt] = (f32x4){0.f, 0.f, 0.f, 0.f};

  for (int kt = 0; kt < S_ / 64; kt++) {
    __syncthreads();   // all waves done reading LDS of tile kt-1
    // stage tile kt from registers (vmcnt wait auto-inserted for the loads)
    *(uint2*)&K2s[rr][cc] = kreg;
    *(uint2*)&Vt [rr][cc] = vreg;
    __syncthreads();   // staged

    // T14: issue tile kt+1's global loads NOW; they drain during compute
    if (kt + 1 < S_ / 64) {
      kreg = *(const uint2*)&K2b[(krow0 + (kt + 1) * 64 + rr) * D_ + trow + cc];
      vreg = *(const uint2*)&QT [(trow + rr) * M_ + krow0 + (kt + 1) * 64 + cc];
    }

    bf16x8 k2f[4][2], vf[4][2];
    #pragma unroll
    for (int nt = 0; nt < 4; nt++)
      #pragma unroll
      for (int kk = 0; kk < 2; kk++) {
        k2f[nt][kk] = *(const bf16x8*)&K2s[nt * 16 + l16][kk * 32 + quad * 8];
        vf[nt][kk]  = *(const bf16x8*)&Vt [nt * 16 + l16][kk * 32 + quad * 8];
      }

    f32x4 sc[4];
    #pragma unroll
    for (int nt = 0; nt < 4; nt++) sc[nt] = (f32x4){0.f, 0.f, 0.f, 0.f};
    __builtin_amdgcn_s_setprio(1);
    #pragma unroll
    for (int kk = 0; kk < 2; kk++)
      #pragma unroll
      for (int nt = 0; nt < 4; nt++)
        sc[nt] = __builtin_amdgcn_mfma_f32_16x16x32_bf16(k2f[nt][kk], qfrag[kk], sc[nt], 0, 0, 0);
    __builtin_amdgcn_s_setprio(0);

    // p = exp2(c2*sc - 12); accumulate row-sum; pack pairs -> Psh
    #pragma unroll
    for (int nt = 0; nt < 4; nt++) {
      float p0 = fast_exp2(fmaf(sc[nt][0], c2, -12.f));
      float p1 = fast_exp2(fmaf(sc[nt][1], c2, -12.f));
      float p2 = fast_exp2(fmaf(sc[nt][2], c2, -12.f));
      float p3 = fast_exp2(fmaf(sc[nt][3], c2, -12.f));
      rl += (p0 + p1) + (p2 + p3);
      const uint2 pk = {cvtpk(p0, p1), cvtpk(p2, p3)};
      *(uint2*)&Psh[w][l16][nt * 16 + quad * 4] = pk;
    }

    #pragma unroll
    for (int kk = 0; kk < 2; kk++) {
      const bf16x8 pf = *(const bf16x8*)&Psh[w][l16][kk * 32 + quad * 8];
      __builtin_amdgcn_s_setprio(1);
      #pragma unroll
      for (int dt = 0; dt < 4; dt++)
        Ot[dt] = __builtin_amdgcn_mfma_f32_16x16x32_bf16(vf[dt][kk], pf, Ot[dt], 0, 0, 0);
      __builtin_amdgcn_s_setprio(0);
    }
  }

  // final row-sum across quads, then write O / l
  {
    float li = rl;
    li += __shfl_xor(li, 16);
    li += __shfl_xor(li, 32);
    const float inv = 1.f / fmaxf(li, 1e-35f);
    const size_t orow = (qrow0 + w * 16 + l16) * D_ + trow;
    #pragma unroll
    for (int dt = 0; dt < 4; dt++) {
      const float4 o = {Ot[dt][0] * inv, Ot[dt][1] * inv,
                        Ot[dt][2] * inv, Ot[dt][3] * inv};
      *(float4*)&out[orow + dt * 16 + quad * 4] = o;
    }
  }
}

extern "C" void kernel_launch(void* const* d_in, const int* in_sizes, int n_in,
                              void* d_out, int out_size, void* d_ws, size_t ws_size,
                              hipStream_t stream) {
  const float* hs  = (const float*)d_in[0];
  const int*   msk = (const int*)d_in[1];
  const float* Wq  = (const float*)d_in[2];
  const float* bq  = (const float*)d_in[3];
  const float* Wk  = (const float*)d_in[4];
  const float* bk  = (const float*)d_in[5];
  float* out = (float*)d_out;

  unsigned short* QT  = (unsigned short*)d_ws;             // [H*64][M_]  8 MB
  unsigned short* K2b = QT  + (size_t)D_ * M_;             // [M_][D_]    8 MB
  unsigned short* WqT = K2b + (size_t)M_ * D_;             // [D_][D_]    2 MB
  unsigned short* WkT = WqT + (size_t)D_ * D_;             // [D_][D_]    2 MB

  prep_w<<<dim3(D_ / 64, D_ / 64, 2), 256, 0, stream>>>(Wq, Wk, WqT, WkT);
  proj_kernel<<<dim3(M_ / 128, D_ / 64), 256, 0, stream>>>(hs, WqT, WkT, bq, bk, K2b, QT);
  attn_kernel<<<dim3(S_ / 256, B_ * H_), 1024, 0, stream>>>(QT, K2b, msk, out);
}

// Round 7
// 167.955 us; speedup vs baseline: 1.1671x; 1.0837x over previous
//
#include <hip/hip_runtime.h>
#include <hip/hip_bf16.h>
#include <math.h>

#define B_  2
#define S_  2048
#define D_  1024
#define H_  16
#define DH_ 64
#define M_  (B_ * S_)   // 4096 tokens

typedef __attribute__((ext_vector_type(8))) short bf16x8;  // 8 bf16 (4 VGPRs)
typedef __attribute__((ext_vector_type(4))) float f32x4;   // MFMA C/D frag

__device__ __forceinline__ float fast_exp2(float x) {
  return __builtin_amdgcn_exp2f(x);   // v_exp_f32
}

__device__ __forceinline__ unsigned short f2bf(float f) {
  union { float f; unsigned u; } c; c.f = f;
  unsigned u = c.u;
  return (unsigned short)((u + 0x7FFFu + ((u >> 16) & 1u)) >> 16);  // RNE
}

// pack two floats -> one dword of 2 bf16 via HW cvt (1 VALU instr)
__device__ __forceinline__ unsigned cvtpk(float lo, float hi) {
  unsigned r;
  asm("v_cvt_pk_bf16_f32 %0, %1, %2" : "=v"(r) : "v"(lo), "v"(hi));
  return r;
}

__device__ __forceinline__ float logsig(float x) {
  // stable log_sigmoid; __logf ok: e in (0,1], result feeds bf16 anyway
  const float e = __expf(-fabsf(x));
  return fminf(x, 0.f) - __logf(1.f + e);
}

// ---------------------------------------------------------------------------
// Kernel 0: transpose Wq/Wk (fp32 [K][N]) -> bf16 W^T [N][K]
// ---------------------------------------------------------------------------
__global__ __launch_bounds__(256) void prep_w(
    const float* __restrict__ Wq, const float* __restrict__ Wk,
    unsigned short* __restrict__ WqT, unsigned short* __restrict__ WkT)
{
  __shared__ unsigned short T[64][72];
  const int tid = threadIdx.x;
  const int k0 = blockIdx.x * 64;
  const int n0 = blockIdx.y * 64;
  const float* W = blockIdx.z ? Wk : Wq;
  unsigned short* WT = blockIdx.z ? WkT : WqT;

  const int kr = tid >> 2, nc = (tid & 3) * 16;
  #pragma unroll
  for (int i = 0; i < 4; i++) {
    const float4 v = *(const float4*)&W[(size_t)(k0 + kr) * D_ + n0 + nc + i * 4];
    T[nc + i * 4 + 0][kr] = f2bf(v.x);
    T[nc + i * 4 + 1][kr] = f2bf(v.y);
    T[nc + i * 4 + 2][kr] = f2bf(v.z);
    T[nc + i * 4 + 3][kr] = f2bf(v.w);
  }
  __syncthreads();
  const int nr = tid >> 2, kc = (tid & 3) * 16;
  const uint4 a = *(const uint4*)&T[nr][kc];
  const uint4 b = *(const uint4*)&T[nr][kc + 8];
  *(uint4*)&WT[(size_t)(n0 + nr) * D_ + k0 + kc] = a;
  *(uint4*)&WT[(size_t)(n0 + nr) * D_ + k0 + kc + 8] = b;
}

// ---------------------------------------------------------------------------
// Kernel 1: Q = hs@Wq+bq ; K2 = logsig(logsig(Q)+Q+hs@Wk+bk)
//   A-operand read DIRECTLY from fp32 hs; prefetched float4s converted via
//   v_cvt_pk_bf16_f32 at ds_write time.
// Round-7: 512 THREADS / 8 WAVES (was 256/4). Same 128m x 64n tile, each
// wave owns ONE 16-m subtile. Grid unchanged (512 blocks) -> 2 blocks/CU =
// 16 waves/CU = 4/SIMD (was 2/SIMD). Same 2-barrier + T14 issue-early sync
// skeleton (verified r3/r4). proj was every-pipe-idle latency-bound
// (MfmaUtil 5%, VALU 27%, HBM 4%) — the r5 attn transformation applied.
// ---------------------------------------------------------------------------
__global__ __launch_bounds__(512, 4) void proj_kernel(
    const float* __restrict__ hs,
    const unsigned short* __restrict__ WqT, const unsigned short* __restrict__ WkT,
    const float* __restrict__ bqv, const float* __restrict__ bkv,
    unsigned short* __restrict__ K2b, unsigned short* __restrict__ QT)
{
  __shared__ unsigned short Ash[128][72];     // hs tile [m][k] (bf16)
  __shared__ unsigned short Bsh[2][64][72];   // W^T tiles [n][k]

  const int tid  = threadIdx.x;
  const int w    = tid >> 6;          // 0..7, owns m rows [w*16, w*16+16)
  const int lane = tid & 63;
  const int quad = lane >> 4;
  const int l16  = lane & 15;
  const int m0 = blockIdx.x * 128;
  const int n0 = blockIdx.y * 64;     // = head * 64

  float bqs[4], bks[4];
  #pragma unroll
  for (int nt = 0; nt < 4; nt++) {
    bqs[nt] = bqv[n0 + nt * 16 + l16];
    bks[nt] = bkv[n0 + nt * 16 + l16];
  }

  f32x4 accQ[4], accK[4];
  #pragma unroll
  for (int nt = 0; nt < 4; nt++) {
    accQ[nt] = (f32x4){0.f, 0.f, 0.f, 0.f};
    accK[nt] = (f32x4){0.f, 0.f, 0.f, 0.f};
  }

  // staging decomposition for 512 threads
  const int am = tid >> 2, ac = (tid & 3) * 16;   // A: 128 rows, 16 fp32/thread
  const int bn = tid >> 3, bc = (tid & 7) * 8;    // B: 64 rows, 8 bf16/thread/mat

  // ---- preload K-tile 0 into registers (T14 issue-early) ----
  float4 Af[4];
  uint4 Bq, Bk;
  {
    const size_t ra = (size_t)(m0 + am) * D_ + ac;
    #pragma unroll
    for (int i = 0; i < 4; i++) Af[i] = *(const float4*)&hs[ra + i * 4];
    const size_t rb = (size_t)(n0 + bn) * D_ + bc;
    Bq = *(const uint4*)&WqT[rb];
    Bk = *(const uint4*)&WkT[rb];
  }

  for (int k0 = 0; k0 < D_; k0 += 64) {
    if (k0) __syncthreads();   // all waves done reading the previous tile
    // stage tile k0 from registers; fp32 A converted to bf16 here
    {
      uint4 t0, t1;
      t0.x = cvtpk(Af[0].x, Af[0].y);  t0.y = cvtpk(Af[0].z, Af[0].w);
      t0.z = cvtpk(Af[1].x, Af[1].y);  t0.w = cvtpk(Af[1].z, Af[1].w);
      t1.x = cvtpk(Af[2].x, Af[2].y);  t1.y = cvtpk(Af[2].z, Af[2].w);
      t1.z = cvtpk(Af[3].x, Af[3].y);  t1.w = cvtpk(Af[3].z, Af[3].w);
      *(uint4*)&Ash[am][ac]     = t0;
      *(uint4*)&Ash[am][ac + 8] = t1;
    }
    *(uint4*)&Bsh[0][bn][bc] = Bq;
    *(uint4*)&Bsh[1][bn][bc] = Bk;
    __syncthreads();           // staged

    // issue tile k0+64's global loads NOW; they drain during compute
    if (k0 + 64 < D_) {
      const size_t ra = (size_t)(m0 + am) * D_ + (k0 + 64) + ac;
      #pragma unroll
      for (int i = 0; i < 4; i++) Af[i] = *(const float4*)&hs[ra + i * 4];
      const size_t rb = (size_t)(n0 + bn) * D_ + (k0 + 64) + bc;
      Bq = *(const uint4*)&WqT[rb];
      Bk = *(const uint4*)&WkT[rb];
    }

    #pragma unroll
    for (int kk = 0; kk < 2; kk++) {
      const bf16x8 af = *(const bf16x8*)&Ash[w * 16 + l16][kk * 32 + quad * 8];
      #pragma unroll
      for (int nt = 0; nt < 4; nt++) {
        const bf16x8 bq = *(const bf16x8*)&Bsh[0][nt * 16 + l16][kk * 32 + quad * 8];
        const bf16x8 bk = *(const bf16x8*)&Bsh[1][nt * 16 + l16][kk * 32 + quad * 8];
        accQ[nt] = __builtin_amdgcn_mfma_f32_16x16x32_bf16(af, bq, accQ[nt], 0, 0, 0);
        accK[nt] = __builtin_amdgcn_mfma_f32_16x16x32_bf16(af, bk, accK[nt], 0, 0, 0);
      }
    }
  }
  __syncthreads();   // protect epilogue's reuse of Bsh as Qt

  // epilogue: bias + logsigmoid chain; K2 row-major stores; Q -> LDS transpose
  unsigned short* Qt = &Bsh[0][0][0];   // 64*136 = 8704 shorts <= 9216 avail
  #pragma unroll
  for (int nt = 0; nt < 4; nt++) {
    float qv[4];
    #pragma unroll
    for (int r = 0; r < 4; r++) {
      const float q  = accQ[nt][r] + bqs[nt];
      const float kr = accK[nt][r] + bks[nt];
      const float k2 = logsig(logsig(q) + q + kr);
      const int m = m0 + w * 16 + quad * 4 + r;
      K2b[(size_t)m * D_ + n0 + nt * 16 + l16] = f2bf(k2);
      qv[r] = q;
    }
    const ushort4 qu = {f2bf(qv[0]), f2bf(qv[1]), f2bf(qv[2]), f2bf(qv[3])};
    *(ushort4*)&Qt[(nt * 16 + l16) * 136 + w * 16 + quad * 4] = qu;
  }
  __syncthreads();
  {
    const int dr = tid >> 3, mc = (tid & 7) * 16;
    #pragma unroll
    for (int i = 0; i < 2; i++) {
      const uint4 v = *(const uint4*)&Qt[dr * 136 + mc + i * 8];
      *(uint4*)&QT[(size_t)(n0 + dr) * M_ + m0 + mc + i * 8] = v;
    }
  }
}

// ---------------------------------------------------------------------------
// Kernel 2: flash attention, S^T formulation, FIXED-SHIFT softmax.
//   s2 = c2 * sc (exp2 domain); p = exp2(s2 - 12). Shift-invariance makes a
//   constant shift exact; no max-reduce, no rescale.
// (byte-identical to verified round 6: QBLK 256, 1024 thr, 16 waves,
//  1 block/CU, 2-barrier + T14 staging, Qa swizzle, cvtpk, setprio)
// ---------------------------------------------------------------------------
__global__ __launch_bounds__(1024) void attn_kernel(
    const unsigned short* __restrict__ QT,
    const unsigned short* __restrict__ K2b,
    const int* __restrict__ mask,
    float* __restrict__ out)
{
  __shared__ unsigned short Qa [256][72];   // Q [q][d], col-swizzled
  __shared__ unsigned short K2s[64][72];    // K2 [key][d]
  __shared__ unsigned short Vt [64][72];    // V^T [d][key]
  __shared__ unsigned short Psh[16][16][72];// per-wave P [q16][key64]

  const int tid  = threadIdx.x;
  const int w    = tid >> 6;          // 0..15
  const int lane = tid & 63;
  const int quad = lane >> 4;
  const int l16  = lane & 15;

  const int qt = blockIdx.x;          // 0..7
  const int bh = blockIdx.y;          // 0..31
  const int b = bh >> 4, h = bh & 15;
  const size_t qrow0 = (size_t)b * S_ + (size_t)qt * 256;
  const size_t krow0 = (size_t)b * S_;
  const size_t trow  = (size_t)h * 64;

  // ---- preload K/V tile 0 into registers (T14 issue-early) ----
  const int rr = tid >> 4, cc = (tid & 15) * 4;
  uint2 kreg, vreg;
  {
    kreg = *(const uint2*)&K2b[(krow0 + rr) * D_ + trow + cc];
    vreg = *(const uint2*)&QT [(trow + rr) * M_ + krow0 + cc];
  }

  // ---- stage Qa [256 q][64 d] from QT (once per block), swizzled cols ----
  {
    const int dr = tid >> 4, qg = tid & 15;
    const int qc = qg * 16;
    const int dcol = dr ^ ((qg & 7) << 3);
    #pragma unroll
    for (int i = 0; i < 2; i++) {
      const uint4 v = *(const uint4*)&QT[(trow + dr) * M_ + qrow0 + qc + i * 8];
      const unsigned short* p = (const unsigned short*)&v;
      #pragma unroll
      for (int j = 0; j < 8; j++) Qa[qc + i * 8 + j][dcol] = p[j];
    }
  }
  __syncthreads();

  // Q fragments (B-operand): read with wave-uniform un-swizzle XOR (free)
  bf16x8 qfrag[2];
  #pragma unroll
  for (int kk = 0; kk < 2; kk++)
    qfrag[kk] =
        *(const bf16x8*)&Qa[w * 16 + l16][(kk * 32 + quad * 8) ^ ((w & 7) << 3)];

  // c2 = -(1/8)*log2(e)*msk ; fixed shift of 12 in exp2 domain
  const float c2 = (mask[qrow0 + w * 16 + l16] != 0) ? -0.18033688f : 0.f;
  float rl = 0.f;

  f32x4 Ot[4];
  #pragma unroll
  for (int dt = 0; dt < 4; dt++) Ot[dt] = (f32x4){0.f, 0.f, 0.f, 0.f};

  for (int kt = 0; kt < S_ / 64; kt++) {
    __syncthreads();   // all waves done reading LDS of tile kt-1
    // stage tile kt from registers (vmcnt wait auto-inserted for the loads)
    *(uint2*)&K2s[rr][cc] = kreg;
    *(uint2*)&Vt [rr][cc] = vreg;
    __syncthreads();   // staged

    // T14: issue tile kt+1's global loads NOW; they drain during compute
    if (kt + 1 < S_ / 64) {
      kreg = *(const uint2*)&K2b[(krow0 + (kt + 1) * 64 + rr) * D_ + trow + cc];
      vreg = *(const uint2*)&QT [(trow + rr) * M_ + krow0 + (kt + 1) * 64 + cc];
    }

    bf16x8 k2f[4][2], vf[4][2];
    #pragma unroll
    for (int nt = 0; nt < 4; nt++)
      #pragma unroll
      for (int kk = 0; kk < 2; kk++) {
        k2f[nt][kk] = *(const bf16x8*)&K2s[nt * 16 + l16][kk * 32 + quad * 8];
        vf[nt][kk]  = *(const bf16x8*)&Vt [nt * 16 + l16][kk * 32 + quad * 8];
      }

    f32x4 sc[4];
    #pragma unroll
    for (int nt = 0; nt < 4; nt++) sc[nt] = (f32x4){0.f, 0.f, 0.f, 0.f};
    __builtin_amdgcn_s_setprio(1);
    #pragma unroll
    for (int kk = 0; kk < 2; kk++)
      #pragma unroll
      for (int nt = 0; nt < 4; nt++)
        sc[nt] = __builtin_amdgcn_mfma_f32_16x16x32_bf16(k2f[nt][kk], qfrag[kk], sc[nt], 0, 0, 0);
    __builtin_amdgcn_s_setprio(0);

    // p = exp2(c2*sc - 12); accumulate row-sum; pack pairs -> Psh
    #pragma unroll
    for (int nt = 0; nt < 4; nt++) {
      float p0 = fast_exp2(fmaf(sc[nt][0], c2, -12.f));
      float p1 = fast_exp2(fmaf(sc[nt][1], c2, -12.f));
      float p2 = fast_exp2(fmaf(sc[nt][2], c2, -12.f));
      float p3 = fast_exp2(fmaf(sc[nt][3], c2, -12.f));
      rl += (p0 + p1) + (p2 + p3);
      const uint2 pk = {cvtpk(p0, p1), cvtpk(p2, p3)};
      *(uint2*)&Psh[w][l16][nt * 16 + quad * 4] = pk;
    }

    #pragma unroll
    for (int kk = 0; kk < 2; kk++) {
      const bf16x8 pf = *(const bf16x8*)&Psh[w][l16][kk * 32 + quad * 8];
      __builtin_amdgcn_s_setprio(1);
      #pragma unroll
      for (int dt = 0; dt < 4; dt++)
        Ot[dt] = __builtin_amdgcn_mfma_f32_16x16x32_bf16(vf[dt][kk], pf, Ot[dt], 0, 0, 0);
      __builtin_amdgcn_s_setprio(0);
    }
  }

  // final row-sum across quads, then write O / l
  {
    float li = rl;
    li += __shfl_xor(li, 16);
    li += __shfl_xor(li, 32);
    const float inv = 1.f / fmaxf(li, 1e-35f);
    const size_t orow = (qrow0 + w * 16 + l16) * D_ + trow;
    #pragma unroll
    for (int dt = 0; dt < 4; dt++) {
      const float4 o = {Ot[dt][0] * inv, Ot[dt][1] * inv,
                        Ot[dt][2] * inv, Ot[dt][3] * inv};
      *(float4*)&out[orow + dt * 16 + quad * 4] = o;
    }
  }
}

extern "C" void kernel_launch(void* const* d_in, const int* in_sizes, int n_in,
                              void* d_out, int out_size, void* d_ws, size_t ws_size,
                              hipStream_t stream) {
  const float* hs  = (const float*)d_in[0];
  const int*   msk = (const int*)d_in[1];
  const float* Wq  = (const float*)d_in[2];
  const float* bq  = (const float*)d_in[3];
  const float* Wk  = (const float*)d_in[4];
  const float* bk  = (const float*)d_in[5];
  float* out = (float*)d_out;

  unsigned short* QT  = (unsigned short*)d_ws;             // [H*64][M_]  8 MB
  unsigned short* K2b = QT  + (size_t)D_ * M_;             // [M_][D_]    8 MB
  unsigned short* WqT = K2b + (size_t)M_ * D_;             // [D_][D_]    2 MB
  unsigned short* WkT = WqT + (size_t)D_ * D_;             // [D_][D_]    2 MB

  prep_w<<<dim3(D_ / 64, D_ / 64, 2), 256, 0, stream>>>(Wq, Wk, WqT, WkT);
  proj_kernel<<<dim3(M_ / 128, D_ / 64), 512, 0, stream>>>(hs, WqT, WkT, bq, bk, K2b, QT);
  attn_kernel<<<dim3(S_ / 256, B_ * H_), 1024, 0, stream>>>(QT, K2b, msk, out);
}

// Round 8
// 155.535 us; speedup vs baseline: 1.2603x; 1.0799x over previous
//
#include <hip/hip_runtime.h>
#include <hip/hip_bf16.h>
#include <math.h>

#define B_  2
#define S_  2048
#define D_  1024
#define H_  16
#define DH_ 64
#define M_  (B_ * S_)   // 4096 tokens

typedef __attribute__((ext_vector_type(8))) short bf16x8;   // 8 bf16 (4 VGPRs)
typedef __attribute__((ext_vector_type(4))) float f32x4;    // 16x16 MFMA C/D
typedef __attribute__((ext_vector_type(16))) float f32x16;  // 32x32 MFMA C/D

__device__ __forceinline__ float fast_exp2(float x) {
  return __builtin_amdgcn_exp2f(x);   // v_exp_f32
}

__device__ __forceinline__ unsigned short f2bf(float f) {
  union { float f; unsigned u; } c; c.f = f;
  unsigned u = c.u;
  return (unsigned short)((u + 0x7FFFu + ((u >> 16) & 1u)) >> 16);  // RNE
}

// pack two floats -> one dword of 2 bf16 via HW cvt (1 VALU instr)
__device__ __forceinline__ unsigned cvtpk(float lo, float hi) {
  unsigned r;
  asm("v_cvt_pk_bf16_f32 %0, %1, %2" : "=v"(r) : "v"(lo), "v"(hi));
  return r;
}

__device__ __forceinline__ float logsig(float x) {
  // stable log_sigmoid; __logf ok: e in (0,1], result feeds bf16 anyway
  const float e = __expf(-fabsf(x));
  return fminf(x, 0.f) - __logf(1.f + e);
}

// ---------------------------------------------------------------------------
// Kernel 0: transpose Wq/Wk (fp32 [K][N]) -> bf16 W^T [N][K]
// ---------------------------------------------------------------------------
__global__ __launch_bounds__(256) void prep_w(
    const float* __restrict__ Wq, const float* __restrict__ Wk,
    unsigned short* __restrict__ WqT, unsigned short* __restrict__ WkT)
{
  __shared__ unsigned short T[64][72];
  const int tid = threadIdx.x;
  const int k0 = blockIdx.x * 64;
  const int n0 = blockIdx.y * 64;
  const float* W = blockIdx.z ? Wk : Wq;
  unsigned short* WT = blockIdx.z ? WkT : WqT;

  const int kr = tid >> 2, nc = (tid & 3) * 16;
  #pragma unroll
  for (int i = 0; i < 4; i++) {
    const float4 v = *(const float4*)&W[(size_t)(k0 + kr) * D_ + n0 + nc + i * 4];
    T[nc + i * 4 + 0][kr] = f2bf(v.x);
    T[nc + i * 4 + 1][kr] = f2bf(v.y);
    T[nc + i * 4 + 2][kr] = f2bf(v.z);
    T[nc + i * 4 + 3][kr] = f2bf(v.w);
  }
  __syncthreads();
  const int nr = tid >> 2, kc = (tid & 3) * 16;
  const uint4 a = *(const uint4*)&T[nr][kc];
  const uint4 b = *(const uint4*)&T[nr][kc + 8];
  *(uint4*)&WT[(size_t)(n0 + nr) * D_ + k0 + kc] = a;
  *(uint4*)&WT[(size_t)(n0 + nr) * D_ + k0 + kc + 8] = b;
}

// ---------------------------------------------------------------------------
// Kernel 1: Q = hs@Wq+bq ; K2 = logsig(logsig(Q)+Q+hs@Wk+bk)
//   (verbatim from verified round 7: 512 thr / 8 waves, T14 staging,
//    fp32 A loaded direct + cvtpk at ds_write)
// ---------------------------------------------------------------------------
__global__ __launch_bounds__(512, 4) void proj_kernel(
    const float* __restrict__ hs,
    const unsigned short* __restrict__ WqT, const unsigned short* __restrict__ WkT,
    const float* __restrict__ bqv, const float* __restrict__ bkv,
    unsigned short* __restrict__ K2b, unsigned short* __restrict__ QT)
{
  __shared__ unsigned short Ash[128][72];     // hs tile [m][k] (bf16)
  __shared__ unsigned short Bsh[2][64][72];   // W^T tiles [n][k]

  const int tid  = threadIdx.x;
  const int w    = tid >> 6;          // 0..7, owns m rows [w*16, w*16+16)
  const int lane = tid & 63;
  const int quad = lane >> 4;
  const int l16  = lane & 15;
  const int m0 = blockIdx.x * 128;
  const int n0 = blockIdx.y * 64;     // = head * 64

  float bqs[4], bks[4];
  #pragma unroll
  for (int nt = 0; nt < 4; nt++) {
    bqs[nt] = bqv[n0 + nt * 16 + l16];
    bks[nt] = bkv[n0 + nt * 16 + l16];
  }

  f32x4 accQ[4], accK[4];
  #pragma unroll
  for (int nt = 0; nt < 4; nt++) {
    accQ[nt] = (f32x4){0.f, 0.f, 0.f, 0.f};
    accK[nt] = (f32x4){0.f, 0.f, 0.f, 0.f};
  }

  const int am = tid >> 2, ac = (tid & 3) * 16;   // A: 128 rows, 16 fp32/thread
  const int bn = tid >> 3, bc = (tid & 7) * 8;    // B: 64 rows, 8 bf16/thread/mat

  // ---- preload K-tile 0 into registers (T14 issue-early) ----
  float4 Af[4];
  uint4 Bq, Bk;
  {
    const size_t ra = (size_t)(m0 + am) * D_ + ac;
    #pragma unroll
    for (int i = 0; i < 4; i++) Af[i] = *(const float4*)&hs[ra + i * 4];
    const size_t rb = (size_t)(n0 + bn) * D_ + bc;
    Bq = *(const uint4*)&WqT[rb];
    Bk = *(const uint4*)&WkT[rb];
  }

  for (int k0 = 0; k0 < D_; k0 += 64) {
    if (k0) __syncthreads();   // all waves done reading the previous tile
    // stage tile k0 from registers; fp32 A converted to bf16 here
    {
      uint4 t0, t1;
      t0.x = cvtpk(Af[0].x, Af[0].y);  t0.y = cvtpk(Af[0].z, Af[0].w);
      t0.z = cvtpk(Af[1].x, Af[1].y);  t0.w = cvtpk(Af[1].z, Af[1].w);
      t1.x = cvtpk(Af[2].x, Af[2].y);  t1.y = cvtpk(Af[2].z, Af[2].w);
      t1.z = cvtpk(Af[3].x, Af[3].y);  t1.w = cvtpk(Af[3].z, Af[3].w);
      *(uint4*)&Ash[am][ac]     = t0;
      *(uint4*)&Ash[am][ac + 8] = t1;
    }
    *(uint4*)&Bsh[0][bn][bc] = Bq;
    *(uint4*)&Bsh[1][bn][bc] = Bk;
    __syncthreads();           // staged

    // issue tile k0+64's global loads NOW; they drain during compute
    if (k0 + 64 < D_) {
      const size_t ra = (size_t)(m0 + am) * D_ + (k0 + 64) + ac;
      #pragma unroll
      for (int i = 0; i < 4; i++) Af[i] = *(const float4*)&hs[ra + i * 4];
      const size_t rb = (size_t)(n0 + bn) * D_ + (k0 + 64) + bc;
      Bq = *(const uint4*)&WqT[rb];
      Bk = *(const uint4*)&WkT[rb];
    }

    #pragma unroll
    for (int kk = 0; kk < 2; kk++) {
      const bf16x8 af = *(const bf16x8*)&Ash[w * 16 + l16][kk * 32 + quad * 8];
      #pragma unroll
      for (int nt = 0; nt < 4; nt++) {
        const bf16x8 bq = *(const bf16x8*)&Bsh[0][nt * 16 + l16][kk * 32 + quad * 8];
        const bf16x8 bk = *(const bf16x8*)&Bsh[1][nt * 16 + l16][kk * 32 + quad * 8];
        accQ[nt] = __builtin_amdgcn_mfma_f32_16x16x32_bf16(af, bq, accQ[nt], 0, 0, 0);
        accK[nt] = __builtin_amdgcn_mfma_f32_16x16x32_bf16(af, bk, accK[nt], 0, 0, 0);
      }
    }
  }
  __syncthreads();   // protect epilogue's reuse of Bsh as Qt

  // epilogue: bias + logsigmoid chain; K2 row-major stores; Q -> LDS transpose
  unsigned short* Qt = &Bsh[0][0][0];   // 64*136 = 8704 shorts <= 9216 avail
  #pragma unroll
  for (int nt = 0; nt < 4; nt++) {
    float qv[4];
    #pragma unroll
    for (int r = 0; r < 4; r++) {
      const float q  = accQ[nt][r] + bqs[nt];
      const float kr = accK[nt][r] + bks[nt];
      const float k2 = logsig(logsig(q) + q + kr);
      const int m = m0 + w * 16 + quad * 4 + r;
      K2b[(size_t)m * D_ + n0 + nt * 16 + l16] = f2bf(k2);
      qv[r] = q;
    }
    const ushort4 qu = {f2bf(qv[0]), f2bf(qv[1]), f2bf(qv[2]), f2bf(qv[3])};
    *(ushort4*)&Qt[(nt * 16 + l16) * 136 + w * 16 + quad * 4] = qu;
  }
  __syncthreads();
  {
    const int dr = tid >> 3, mc = (tid & 7) * 16;
    #pragma unroll
    for (int i = 0; i < 2; i++) {
      const uint4 v = *(const uint4*)&Qt[dr * 136 + mc + i * 8];
      *(uint4*)&QT[(size_t)(n0 + dr) * M_ + m0 + mc + i * 8] = v;
    }
  }
}

// ---------------------------------------------------------------------------
// Kernel 2: flash attention, S^T formulation, FIXED-SHIFT softmax.
//   s2 = c2 * sc (exp2 domain); p = exp2(s2 - 12). Shift-invariance makes a
//   constant shift exact; no max-reduce, no rescale — and key-split partials
//   (unnormalized O, row-sum l) combine EXACTLY by addition.
// Round-8: 32x32x16 MFMA + key-split waves. attn was LDS-pipe-bound:
// 16 waves x 16 ds_read_b128 frag reads/tile (each wave reads the WHOLE
// K/V tile for only 16 q) ~= 3072 cyc/tile of the ~5K budget. 32x32 MFMA
// does 2x MACs per fragment byte; wave = (qsub = w&7 -> 32 q, ksel = w>>3
// -> 32-key half) -> 8 frag b128/wave/tile (halved per-CU traffic), 8 MFMA.
// Psh shrinks to [32][40]/wave (cvtpk pairs -> aligned b128 B-frags).
// End combine: ksel=1 deposits Ot/l partials in reused Qa LDS; ksel=0 adds,
// normalizes, stores. Staging skeleton (2-barrier + T14 reg prefetch), Qa
// swizzle, K2s/Vt staging all verbatim from verified r6/r7.
// Frag layouts (CDNA 32x32x16): A row=lane&31, k=(lane>>5)*8+j;
// B n=lane&31, same k; C/D col=lane&31, row=(reg&3)+8*(reg>>2)+4*(lane>>5).
// LDS: Qa 36K + K2s 9K + Vt 9K + Psh 40K = 94K -> 1 block/CU, 16 waves.
// ---------------------------------------------------------------------------
__global__ __launch_bounds__(1024) void attn_kernel(
    const unsigned short* __restrict__ QT,
    const unsigned short* __restrict__ K2b,
    const int* __restrict__ mask,
    float* __restrict__ out)
{
  __shared__ unsigned short Qa [256][72];   // Q [q][d], col-swizzled
  __shared__ unsigned short K2s[64][72];    // K2 [key][d]
  __shared__ unsigned short Vt [64][72];    // V^T [d][key]
  __shared__ unsigned short Psh[16][32][40];// per-wave P [q32][key32+pad]

  const int tid  = threadIdx.x;
  const int w    = tid >> 6;           // 0..15
  const int lane = tid & 63;
  const int r31  = lane & 31;          // A-frag row / q column
  const int hi   = lane >> 5;
  const int hi8  = hi * 8;
  const int qsub = w & 7;              // which 32-q group
  const int ksel = w >> 3;             // which 32-key half of each tile

  const int qt = blockIdx.x;           // 0..7
  const int bh = blockIdx.y;           // 0..31
  const int b = bh >> 4, h = bh & 15;
  const size_t qrow0 = (size_t)b * S_ + (size_t)qt * 256;
  const size_t krow0 = (size_t)b * S_;
  const size_t trow  = (size_t)h * 64;

  // ---- preload K/V tile 0 into registers (T14 issue-early) ----
  const int rr = tid >> 4, cc = (tid & 15) * 4;
  uint2 kreg, vreg;
  kreg = *(const uint2*)&K2b[(krow0 + rr) * D_ + trow + cc];
  vreg = *(const uint2*)&QT [(trow + rr) * M_ + krow0 + cc];

  // ---- stage Qa [256 q][64 d], swizzled cols (verbatim r6) ----
  {
    const int dr = tid >> 4, qg = tid & 15;
    const int qc = qg * 16;
    const int dcol = dr ^ ((qg & 7) << 3);
    #pragma unroll
    for (int i = 0; i < 2; i++) {
      const uint4 v = *(const uint4*)&QT[(trow + dr) * M_ + qrow0 + qc + i * 8];
      const unsigned short* p = (const unsigned short*)&v;
      #pragma unroll
      for (int j = 0; j < 8; j++) Qa[qc + i * 8 + j][dcol] = p[j];
    }
  }
  __syncthreads();

  // hoist Q B-frags: frag s covers d = s*16 + hi*8 + j
  bf16x8 qfrag[4];
  {
    const int qrow = qsub * 32 + r31;
    const int g7 = (qrow >> 4) & 7;     // stored-col swizzle group (per-lane)
    #pragma unroll
    for (int s = 0; s < 4; s++)
      qfrag[s] = *(const bf16x8*)&Qa[qrow][(s * 16 + hi8) ^ (g7 << 3)];
  }

  // c2 = -(1/8)*log2(e)*msk ; fixed shift of 12 in exp2 domain
  const float c2 = (mask[qrow0 + qsub * 32 + r31] != 0) ? -0.18033688f : 0.f;
  float rl = 0.f;

  f32x16 Ot0, Ot1;
  #pragma unroll
  for (int r = 0; r < 16; r++) { Ot0[r] = 0.f; Ot1[r] = 0.f; }

  const int NT = S_ / 64;
  for (int kt = 0; kt < NT; kt++) {
    __syncthreads();   // all waves done reading LDS of tile kt-1
    *(uint2*)&K2s[rr][cc] = kreg;
    *(uint2*)&Vt [rr][cc] = vreg;
    __syncthreads();   // staged

    // T14: issue tile kt+1's global loads NOW; they drain during compute
    if (kt + 1 < NT) {
      kreg = *(const uint2*)&K2b[(krow0 + (kt + 1) * 64 + rr) * D_ + trow + cc];
      vreg = *(const uint2*)&QT [(trow + rr) * M_ + krow0 + (kt + 1) * 64 + cc];
    }

    // QK^T: S^T[key][q] for this wave's 32 keys x 32 q, K = 64 d in 4 steps
    bf16x8 kf[4];
    #pragma unroll
    for (int s = 0; s < 4; s++)
      kf[s] = *(const bf16x8*)&K2s[ksel * 32 + r31][s * 16 + hi8];
    f32x16 sc;
    #pragma unroll
    for (int r = 0; r < 16; r++) sc[r] = 0.f;
    __builtin_amdgcn_s_setprio(1);
    #pragma unroll
    for (int s = 0; s < 4; s++)
      sc = __builtin_amdgcn_mfma_f32_32x32x16_bf16(kf[s], qfrag[s], sc, 0, 0, 0);
    __builtin_amdgcn_s_setprio(0);

    // p = exp2(c2*sc - 12); row-sum; cvtpk pairs -> per-wave Psh
    float p[16];
    #pragma unroll
    for (int r = 0; r < 16; r++) p[r] = fast_exp2(fmaf(sc[r], c2, -12.f));
    #pragma unroll
    for (int r = 0; r < 16; r += 4) rl += ((p[r] + p[r+1]) + (p[r+2] + p[r+3]));
    {
      // reg r holds key (r&3) + 8*(r>>2) + 4*hi  -> contiguous uint2 groups
      unsigned short* pr = &Psh[w][r31][0];
      const uint2 g0 = {cvtpk(p[0],  p[1]),  cvtpk(p[2],  p[3])};
      const uint2 g1 = {cvtpk(p[4],  p[5]),  cvtpk(p[6],  p[7])};
      const uint2 g2 = {cvtpk(p[8],  p[9]),  cvtpk(p[10], p[11])};
      const uint2 g3 = {cvtpk(p[12], p[13]), cvtpk(p[14], p[15])};
      *(uint2*)&pr[ 0 + 4 * hi] = g0;
      *(uint2*)&pr[ 8 + 4 * hi] = g1;
      *(uint2*)&pr[16 + 4 * hi] = g2;
      *(uint2*)&pr[24 + 4 * hi] = g3;
    }

    // PV: O^T[d][q] partial over own 32 keys (2 k-steps x 2 d-blocks)
    __builtin_amdgcn_s_setprio(1);
    #pragma unroll
    for (int s2 = 0; s2 < 2; s2++) {
      const bf16x8 pf  = *(const bf16x8*)&Psh[w][r31][s2 * 16 + hi8];
      const bf16x8 vf0 = *(const bf16x8*)&Vt[r31]     [ksel * 32 + s2 * 16 + hi8];
      const bf16x8 vf1 = *(const bf16x8*)&Vt[32 + r31][ksel * 32 + s2 * 16 + hi8];
      Ot0 = __builtin_amdgcn_mfma_f32_32x32x16_bf16(vf0, pf, Ot0, 0, 0, 0);
      Ot1 = __builtin_amdgcn_mfma_f32_32x32x16_bf16(vf1, pf, Ot1, 0, 0, 0);
    }
    __builtin_amdgcn_s_setprio(0);
  }

  // ---- key-split combine: exact (no rescale ever happened) ----
  rl += __shfl_xor(rl, 32);               // q-sum over this wave's 32 keys
  __syncthreads();                         // loop LDS reads all done; reuse Qa/K2s
  float* redO = (float*)&Qa[0][0];         // [8 qsub][16 reg][64 lane] = 32 KB
  float* redL = (float*)&K2s[0][0];        // [8 qsub][64 lane] = 2 KB
  if (ksel == 1) {
    #pragma unroll
    for (int r = 0; r < 16; r++) redO[(qsub * 16 + r) * 64 + lane] = Ot0[r];
    redL[qsub * 64 + lane] = rl;
  }
  __syncthreads();
  float inv = 0.f;
  size_t orow = 0;
  if (ksel == 0) {
    const float lt = rl + redL[qsub * 64 + lane];
    inv = 1.f / fmaxf(lt, 1e-35f);
    orow = (qrow0 + qsub * 32 + r31) * D_ + trow;
    #pragma unroll
    for (int rq = 0; rq < 4; rq++) {       // regs 4rq..4rq+3 -> d = 8rq+4hi+0..3
      float4 o;
      o.x = (Ot0[4*rq+0] + redO[(qsub*16 + 4*rq+0)*64 + lane]) * inv;
      o.y = (Ot0[4*rq+1] + redO[(qsub*16 + 4*rq+1)*64 + lane]) * inv;
      o.z = (Ot0[4*rq+2] + redO[(qsub*16 + 4*rq+2)*64 + lane]) * inv;
      o.w = (Ot0[4*rq+3] + redO[(qsub*16 + 4*rq+3)*64 + lane]) * inv;
      *(float4*)&out[orow + rq * 8 + 4 * hi] = o;
    }
  }
  __syncthreads();
  if (ksel == 1) {
    #pragma unroll
    for (int r = 0; r < 16; r++) redO[(qsub * 16 + r) * 64 + lane] = Ot1[r];
  }
  __syncthreads();
  if (ksel == 0) {
    #pragma unroll
    for (int rq = 0; rq < 4; rq++) {
      float4 o;
      o.x = (Ot1[4*rq+0] + redO[(qsub*16 + 4*rq+0)*64 + lane]) * inv;
      o.y = (Ot1[4*rq+1] + redO[(qsub*16 + 4*rq+1)*64 + lane]) * inv;
      o.z = (Ot1[4*rq+2] + redO[(qsub*16 + 4*rq+2)*64 + lane]) * inv;
      o.w = (Ot1[4*rq+3] + redO[(qsub*16 + 4*rq+3)*64 + lane]) * inv;
      *(float4*)&out[orow + 32 + rq * 8 + 4 * hi] = o;
    }
  }
}

extern "C" void kernel_launch(void* const* d_in, const int* in_sizes, int n_in,
                              void* d_out, int out_size, void* d_ws, size_t ws_size,
                              hipStream_t stream) {
  const float* hs  = (const float*)d_in[0];
  const int*   msk = (const int*)d_in[1];
  const float* Wq  = (const float*)d_in[2];
  const float* bq  = (const float*)d_in[3];
  const float* Wk  = (const float*)d_in[4];
  const float* bk  = (const float*)d_in[5];
  float* out = (float*)d_out;

  unsigned short* QT  = (unsigned short*)d_ws;             // [H*64][M_]  8 MB
  unsigned short* K2b = QT  + (size_t)D_ * M_;             // [M_][D_]    8 MB
  unsigned short* WqT = K2b + (size_t)M_ * D_;             // [D_][D_]    2 MB
  unsigned short* WkT = WqT + (size_t)D_ * D_;             // [D_][D_]    2 MB

  prep_w<<<dim3(D_ / 64, D_ / 64, 2), 256, 0, stream>>>(Wq, Wk, WqT, WkT);
  proj_kernel<<<dim3(M_ / 128, D_ / 64), 512, 0, stream>>>(hs, WqT, WkT, bq, bk, K2b, QT);
  attn_kernel<<<dim3(S_ / 256, B_ * H_), 1024, 0, stream>>>(QT, K2b, msk, out);
}

// Round 9
// 154.474 us; speedup vs baseline: 1.2689x; 1.0069x over previous
//
#include <hip/hip_runtime.h>
#include <hip/hip_bf16.h>
#include <math.h>

#define B_  2
#define S_  2048
#define D_  1024
#define H_  16
#define DH_ 64
#define M_  (B_ * S_)   // 4096 tokens

typedef __attribute__((ext_vector_type(8))) short bf16x8;   // 8 bf16 (4 VGPRs)
typedef __attribute__((ext_vector_type(4))) float f32x4;    // 16x16 MFMA C/D
typedef __attribute__((ext_vector_type(16))) float f32x16;  // 32x32 MFMA C/D
typedef __attribute__((ext_vector_type(2))) unsigned u32x2;

__device__ __forceinline__ float fast_exp2(float x) {
  return __builtin_amdgcn_exp2f(x);   // v_exp_f32
}

__device__ __forceinline__ unsigned short f2bf(float f) {
  union { float f; unsigned u; } c; c.f = f;
  unsigned u = c.u;
  return (unsigned short)((u + 0x7FFFu + ((u >> 16) & 1u)) >> 16);  // RNE
}

// pack two floats -> one dword of 2 bf16 via HW cvt (1 VALU instr)
__device__ __forceinline__ unsigned cvtpk(float lo, float hi) {
  unsigned r;
  asm("v_cvt_pk_bf16_f32 %0, %1, %2" : "=v"(r) : "v"(lo), "v"(hi));
  return r;
}

// T12: swap upper 32 lanes of x with lower 32 lanes of y (both updated)
__device__ __forceinline__ void plswap(unsigned &x, unsigned &y) {
  u32x2 r = __builtin_amdgcn_permlane32_swap(x, y, false, false);
  x = r[0]; y = r[1];
}

__device__ __forceinline__ float logsig(float x) {
  // stable log_sigmoid; __logf ok: e in (0,1], result feeds bf16 anyway
  const float e = __expf(-fabsf(x));
  return fminf(x, 0.f) - __logf(1.f + e);
}

// ---------------------------------------------------------------------------
// Kernel 0: transpose Wq/Wk (fp32 [K][N]) -> bf16 W^T [N][K]
// ---------------------------------------------------------------------------
__global__ __launch_bounds__(256) void prep_w(
    const float* __restrict__ Wq, const float* __restrict__ Wk,
    unsigned short* __restrict__ WqT, unsigned short* __restrict__ WkT)
{
  __shared__ unsigned short T[64][72];
  const int tid = threadIdx.x;
  const int k0 = blockIdx.x * 64;
  const int n0 = blockIdx.y * 64;
  const float* W = blockIdx.z ? Wk : Wq;
  unsigned short* WT = blockIdx.z ? WkT : WqT;

  const int kr = tid >> 2, nc = (tid & 3) * 16;
  #pragma unroll
  for (int i = 0; i < 4; i++) {
    const float4 v = *(const float4*)&W[(size_t)(k0 + kr) * D_ + n0 + nc + i * 4];
    T[nc + i * 4 + 0][kr] = f2bf(v.x);
    T[nc + i * 4 + 1][kr] = f2bf(v.y);
    T[nc + i * 4 + 2][kr] = f2bf(v.z);
    T[nc + i * 4 + 3][kr] = f2bf(v.w);
  }
  __syncthreads();
  const int nr = tid >> 2, kc = (tid & 3) * 16;
  const uint4 a = *(const uint4*)&T[nr][kc];
  const uint4 b = *(const uint4*)&T[nr][kc + 8];
  *(uint4*)&WT[(size_t)(n0 + nr) * D_ + k0 + kc] = a;
  *(uint4*)&WT[(size_t)(n0 + nr) * D_ + k0 + kc + 8] = b;
}

// ---------------------------------------------------------------------------
// Kernel 1: Q = hs@Wq+bq ; K2 = logsig(logsig(Q)+Q+hs@Wk+bk)
//   (verbatim from verified round 7/8: 512 thr / 8 waves, T14 staging,
//    fp32 A loaded direct + cvtpk at ds_write)
// ---------------------------------------------------------------------------
__global__ __launch_bounds__(512, 4) void proj_kernel(
    const float* __restrict__ hs,
    const unsigned short* __restrict__ WqT, const unsigned short* __restrict__ WkT,
    const float* __restrict__ bqv, const float* __restrict__ bkv,
    unsigned short* __restrict__ K2b, unsigned short* __restrict__ QT)
{
  __shared__ unsigned short Ash[128][72];     // hs tile [m][k] (bf16)
  __shared__ unsigned short Bsh[2][64][72];   // W^T tiles [n][k]

  const int tid  = threadIdx.x;
  const int w    = tid >> 6;          // 0..7, owns m rows [w*16, w*16+16)
  const int lane = tid & 63;
  const int quad = lane >> 4;
  const int l16  = lane & 15;
  const int m0 = blockIdx.x * 128;
  const int n0 = blockIdx.y * 64;     // = head * 64

  float bqs[4], bks[4];
  #pragma unroll
  for (int nt = 0; nt < 4; nt++) {
    bqs[nt] = bqv[n0 + nt * 16 + l16];
    bks[nt] = bkv[n0 + nt * 16 + l16];
  }

  f32x4 accQ[4], accK[4];
  #pragma unroll
  for (int nt = 0; nt < 4; nt++) {
    accQ[nt] = (f32x4){0.f, 0.f, 0.f, 0.f};
    accK[nt] = (f32x4){0.f, 0.f, 0.f, 0.f};
  }

  const int am = tid >> 2, ac = (tid & 3) * 16;   // A: 128 rows, 16 fp32/thread
  const int bn = tid >> 3, bc = (tid & 7) * 8;    // B: 64 rows, 8 bf16/thread/mat

  // ---- preload K-tile 0 into registers (T14 issue-early) ----
  float4 Af[4];
  uint4 Bq, Bk;
  {
    const size_t ra = (size_t)(m0 + am) * D_ + ac;
    #pragma unroll
    for (int i = 0; i < 4; i++) Af[i] = *(const float4*)&hs[ra + i * 4];
    const size_t rb = (size_t)(n0 + bn) * D_ + bc;
    Bq = *(const uint4*)&WqT[rb];
    Bk = *(const uint4*)&WkT[rb];
  }

  for (int k0 = 0; k0 < D_; k0 += 64) {
    if (k0) __syncthreads();   // all waves done reading the previous tile
    // stage tile k0 from registers; fp32 A converted to bf16 here
    {
      uint4 t0, t1;
      t0.x = cvtpk(Af[0].x, Af[0].y);  t0.y = cvtpk(Af[0].z, Af[0].w);
      t0.z = cvtpk(Af[1].x, Af[1].y);  t0.w = cvtpk(Af[1].z, Af[1].w);
      t1.x = cvtpk(Af[2].x, Af[2].y);  t1.y = cvtpk(Af[2].z, Af[2].w);
      t1.z = cvtpk(Af[3].x, Af[3].y);  t1.w = cvtpk(Af[3].z, Af[3].w);
      *(uint4*)&Ash[am][ac]     = t0;
      *(uint4*)&Ash[am][ac + 8] = t1;
    }
    *(uint4*)&Bsh[0][bn][bc] = Bq;
    *(uint4*)&Bsh[1][bn][bc] = Bk;
    __syncthreads();           // staged

    // issue tile k0+64's global loads NOW; they drain during compute
    if (k0 + 64 < D_) {
      const size_t ra = (size_t)(m0 + am) * D_ + (k0 + 64) + ac;
      #pragma unroll
      for (int i = 0; i < 4; i++) Af[i] = *(const float4*)&hs[ra + i * 4];
      const size_t rb = (size_t)(n0 + bn) * D_ + (k0 + 64) + bc;
      Bq = *(const uint4*)&WqT[rb];
      Bk = *(const uint4*)&WkT[rb];
    }

    #pragma unroll
    for (int kk = 0; kk < 2; kk++) {
      const bf16x8 af = *(const bf16x8*)&Ash[w * 16 + l16][kk * 32 + quad * 8];
      #pragma unroll
      for (int nt = 0; nt < 4; nt++) {
        const bf16x8 bq = *(const bf16x8*)&Bsh[0][nt * 16 + l16][kk * 32 + quad * 8];
        const bf16x8 bk = *(const bf16x8*)&Bsh[1][nt * 16 + l16][kk * 32 + quad * 8];
        accQ[nt] = __builtin_amdgcn_mfma_f32_16x16x32_bf16(af, bq, accQ[nt], 0, 0, 0);
        accK[nt] = __builtin_amdgcn_mfma_f32_16x16x32_bf16(af, bk, accK[nt], 0, 0, 0);
      }
    }
  }
  __syncthreads();   // protect epilogue's reuse of Bsh as Qt

  // epilogue: bias + logsigmoid chain; K2 row-major stores; Q -> LDS transpose
  unsigned short* Qt = &Bsh[0][0][0];   // 64*136 = 8704 shorts <= 9216 avail
  #pragma unroll
  for (int nt = 0; nt < 4; nt++) {
    float qv[4];
    #pragma unroll
    for (int r = 0; r < 4; r++) {
      const float q  = accQ[nt][r] + bqs[nt];
      const float kr = accK[nt][r] + bks[nt];
      const float k2 = logsig(logsig(q) + q + kr);
      const int m = m0 + w * 16 + quad * 4 + r;
      K2b[(size_t)m * D_ + n0 + nt * 16 + l16] = f2bf(k2);
      qv[r] = q;
    }
    const ushort4 qu = {f2bf(qv[0]), f2bf(qv[1]), f2bf(qv[2]), f2bf(qv[3])};
    *(ushort4*)&Qt[(nt * 16 + l16) * 136 + w * 16 + quad * 4] = qu;
  }
  __syncthreads();
  {
    const int dr = tid >> 3, mc = (tid & 7) * 16;
    #pragma unroll
    for (int i = 0; i < 2; i++) {
      const uint4 v = *(const uint4*)&Qt[dr * 136 + mc + i * 8];
      *(uint4*)&QT[(size_t)(n0 + dr) * M_ + m0 + mc + i * 8] = v;
    }
  }
}

// ---------------------------------------------------------------------------
// Kernel 2: flash attention, S^T formulation, FIXED-SHIFT softmax.
//   s2 = c2 * sc (exp2 domain); p = exp2(s2 - 12). Shift-invariance makes a
//   constant shift exact; no max-reduce, no rescale — and key-split partials
//   (unnormalized O, row-sum l) combine EXACTLY by addition.
// Round-9: T12 in-register P fragments. After swapped QK^T each lane holds
// P[16 keys][its q]; the PV B-frag needs keys s2*16+hi*8+j at the same q.
// 8 cvtpk + 4 permlane32_swap build both pf frags fully in-register:
//   (a',b') = swap(cvtpk(p0,p1), cvtpk(p4,p5)) -> a'={hi0:k01,hi1:k89},
//   b'={hi0:k45,hi1:k(12,13)} = frag dwords 0 and 2 for both halves.
// Eliminates the entire Psh path: -4 ds_write_b64, -2 ds_read_b128, -1
// lgkm serialization per wave per tile, -40 KB LDS. P values bit-identical
// (same cvtpk rounding). Sync structure, staging, 32x32 geometry, key-split
// combine all verbatim from verified round 8.
// LDS: Qa 36K + K2s 9K + Vt 9K = 54 KB.
// ---------------------------------------------------------------------------
__global__ __launch_bounds__(1024) void attn_kernel(
    const unsigned short* __restrict__ QT,
    const unsigned short* __restrict__ K2b,
    const int* __restrict__ mask,
    float* __restrict__ out)
{
  __shared__ unsigned short Qa [256][72];   // Q [q][d], col-swizzled
  __shared__ unsigned short K2s[64][72];    // K2 [key][d]
  __shared__ unsigned short Vt [64][72];    // V^T [d][key]

  const int tid  = threadIdx.x;
  const int w    = tid >> 6;           // 0..15
  const int lane = tid & 63;
  const int r31  = lane & 31;          // A-frag row / q column
  const int hi   = lane >> 5;
  const int hi8  = hi * 8;
  const int qsub = w & 7;              // which 32-q group
  const int ksel = w >> 3;             // which 32-key half of each tile

  const int qt = blockIdx.x;           // 0..7
  const int bh = blockIdx.y;           // 0..31
  const int b = bh >> 4, h = bh & 15;
  const size_t qrow0 = (size_t)b * S_ + (size_t)qt * 256;
  const size_t krow0 = (size_t)b * S_;
  const size_t trow  = (size_t)h * 64;

  // ---- preload K/V tile 0 into registers (T14 issue-early) ----
  const int rr = tid >> 4, cc = (tid & 15) * 4;
  uint2 kreg, vreg;
  kreg = *(const uint2*)&K2b[(krow0 + rr) * D_ + trow + cc];
  vreg = *(const uint2*)&QT [(trow + rr) * M_ + krow0 + cc];

  // ---- stage Qa [256 q][64 d], swizzled cols (verbatim r6) ----
  {
    const int dr = tid >> 4, qg = tid & 15;
    const int qc = qg * 16;
    const int dcol = dr ^ ((qg & 7) << 3);
    #pragma unroll
    for (int i = 0; i < 2; i++) {
      const uint4 v = *(const uint4*)&QT[(trow + dr) * M_ + qrow0 + qc + i * 8];
      const unsigned short* p = (const unsigned short*)&v;
      #pragma unroll
      for (int j = 0; j < 8; j++) Qa[qc + i * 8 + j][dcol] = p[j];
    }
  }
  __syncthreads();

  // hoist Q B-frags: frag s covers d = s*16 + hi*8 + j
  bf16x8 qfrag[4];
  {
    const int qrow = qsub * 32 + r31;
    const int g7 = (qrow >> 4) & 7;     // stored-col swizzle group (per-lane)
    #pragma unroll
    for (int s = 0; s < 4; s++)
      qfrag[s] = *(const bf16x8*)&Qa[qrow][(s * 16 + hi8) ^ (g7 << 3)];
  }

  // c2 = -(1/8)*log2(e)*msk ; fixed shift of 12 in exp2 domain
  const float c2 = (mask[qrow0 + qsub * 32 + r31] != 0) ? -0.18033688f : 0.f;
  float rl = 0.f;

  f32x16 Ot0, Ot1;
  #pragma unroll
  for (int r = 0; r < 16; r++) { Ot0[r] = 0.f; Ot1[r] = 0.f; }

  const int NT = S_ / 64;
  for (int kt = 0; kt < NT; kt++) {
    __syncthreads();   // all waves done reading LDS of tile kt-1
    *(uint2*)&K2s[rr][cc] = kreg;
    *(uint2*)&Vt [rr][cc] = vreg;
    __syncthreads();   // staged

    // T14: issue tile kt+1's global loads NOW; they drain during compute
    if (kt + 1 < NT) {
      kreg = *(const uint2*)&K2b[(krow0 + (kt + 1) * 64 + rr) * D_ + trow + cc];
      vreg = *(const uint2*)&QT [(trow + rr) * M_ + krow0 + (kt + 1) * 64 + cc];
    }

    // QK^T: S^T[key][q] for this wave's 32 keys x 32 q, K = 64 d in 4 steps
    bf16x8 kf[4];
    #pragma unroll
    for (int s = 0; s < 4; s++)
      kf[s] = *(const bf16x8*)&K2s[ksel * 32 + r31][s * 16 + hi8];
    f32x16 sc;
    #pragma unroll
    for (int r = 0; r < 16; r++) sc[r] = 0.f;
    __builtin_amdgcn_s_setprio(1);
    #pragma unroll
    for (int s = 0; s < 4; s++)
      sc = __builtin_amdgcn_mfma_f32_32x32x16_bf16(kf[s], qfrag[s], sc, 0, 0, 0);
    __builtin_amdgcn_s_setprio(0);

    // p = exp2(c2*sc - 12); row-sum; T12 in-register P fragments
    float p[16];
    #pragma unroll
    for (int r = 0; r < 16; r++) p[r] = fast_exp2(fmaf(sc[r], c2, -12.f));
    #pragma unroll
    for (int r = 0; r < 16; r += 4) rl += ((p[r] + p[r+1]) + (p[r+2] + p[r+3]));

    // build pf frags: dwords [a', c', b', d'] per s2 (see header comment)
    unsigned pk0 = cvtpk(p[0],  p[1]),  pk1 = cvtpk(p[2],  p[3]);
    unsigned pk2 = cvtpk(p[4],  p[5]),  pk3 = cvtpk(p[6],  p[7]);
    unsigned pk4 = cvtpk(p[8],  p[9]),  pk5 = cvtpk(p[10], p[11]);
    unsigned pk6 = cvtpk(p[12], p[13]), pk7 = cvtpk(p[14], p[15]);
    plswap(pk0, pk2);   // pk0 -> dword0 (k01 | k89), pk2 -> dword2 (k45 | k12,13)
    plswap(pk1, pk3);   // pk1 -> dword1,             pk3 -> dword3
    plswap(pk4, pk6);
    plswap(pk5, pk7);
    union { unsigned d[8]; bf16x8 v[2]; } pu;
    pu.d[0] = pk0; pu.d[1] = pk1; pu.d[2] = pk2; pu.d[3] = pk3;
    pu.d[4] = pk4; pu.d[5] = pk5; pu.d[6] = pk6; pu.d[7] = pk7;

    // PV: O^T[d][q] partial over own 32 keys (2 k-steps x 2 d-blocks)
    __builtin_amdgcn_s_setprio(1);
    #pragma unroll
    for (int s2 = 0; s2 < 2; s2++) {
      const bf16x8 pf  = pu.v[s2];
      const bf16x8 vf0 = *(const bf16x8*)&Vt[r31]     [ksel * 32 + s2 * 16 + hi8];
      const bf16x8 vf1 = *(const bf16x8*)&Vt[32 + r31][ksel * 32 + s2 * 16 + hi8];
      Ot0 = __builtin_amdgcn_mfma_f32_32x32x16_bf16(vf0, pf, Ot0, 0, 0, 0);
      Ot1 = __builtin_amdgcn_mfma_f32_32x32x16_bf16(vf1, pf, Ot1, 0, 0, 0);
    }
    __builtin_amdgcn_s_setprio(0);
  }

  // ---- key-split combine: exact (no rescale ever happened) ----
  rl += __shfl_xor(rl, 32);               // q-sum over this wave's 32 keys
  __syncthreads();                         // loop LDS reads all done; reuse Qa/K2s
  float* redO = (float*)&Qa[0][0];         // [8 qsub][16 reg][64 lane] = 32 KB
  float* redL = (float*)&K2s[0][0];        // [8 qsub][64 lane] = 2 KB
  if (ksel == 1) {
    #pragma unroll
    for (int r = 0; r < 16; r++) redO[(qsub * 16 + r) * 64 + lane] = Ot0[r];
    redL[qsub * 64 + lane] = rl;
  }
  __syncthreads();
  float inv = 0.f;
  size_t orow = 0;
  if (ksel == 0) {
    const float lt = rl + redL[qsub * 64 + lane];
    inv = 1.f / fmaxf(lt, 1e-35f);
    orow = (qrow0 + qsub * 32 + r31) * D_ + trow;
    #pragma unroll
    for (int rq = 0; rq < 4; rq++) {       // regs 4rq..4rq+3 -> d = 8rq+4hi+0..3
      float4 o;
      o.x = (Ot0[4*rq+0] + redO[(qsub*16 + 4*rq+0)*64 + lane]) * inv;
      o.y = (Ot0[4*rq+1] + redO[(qsub*16 + 4*rq+1)*64 + lane]) * inv;
      o.z = (Ot0[4*rq+2] + redO[(qsub*16 + 4*rq+2)*64 + lane]) * inv;
      o.w = (Ot0[4*rq+3] + redO[(qsub*16 + 4*rq+3)*64 + lane]) * inv;
      *(float4*)&out[orow + rq * 8 + 4 * hi] = o;
    }
  }
  __syncthreads();
  if (ksel == 1) {
    #pragma unroll
    for (int r = 0; r < 16; r++) redO[(qsub * 16 + r) * 64 + lane] = Ot1[r];
  }
  __syncthreads();
  if (ksel == 0) {
    #pragma unroll
    for (int rq = 0; rq < 4; rq++) {
      float4 o;
      o.x = (Ot1[4*rq+0] + redO[(qsub*16 + 4*rq+0)*64 + lane]) * inv;
      o.y = (Ot1[4*rq+1] + redO[(qsub*16 + 4*rq+1)*64 + lane]) * inv;
      o.z = (Ot1[4*rq+2] + redO[(qsub*16 + 4*rq+2)*64 + lane]) * inv;
      o.w = (Ot1[4*rq+3] + redO[(qsub*16 + 4*rq+3)*64 + lane]) * inv;
      *(float4*)&out[orow + 32 + rq * 8 + 4 * hi] = o;
    }
  }
}

extern "C" void kernel_launch(void* const* d_in, const int* in_sizes, int n_in,
                              void* d_out, int out_size, void* d_ws, size_t ws_size,
                              hipStream_t stream) {
  const float* hs  = (const float*)d_in[0];
  const int*   msk = (const int*)d_in[1];
  const float* Wq  = (const float*)d_in[2];
  const float* bq  = (const float*)d_in[3];
  const float* Wk  = (const float*)d_in[4];
  const float* bk  = (const float*)d_in[5];
  float* out = (float*)d_out;

  unsigned short* QT  = (unsigned short*)d_ws;             // [H*64][M_]  8 MB
  unsigned short* K2b = QT  + (size_t)D_ * M_;             // [M_][D_]    8 MB
  unsigned short* WqT = K2b + (size_t)M_ * D_;             // [D_][D_]    2 MB
  unsigned short* WkT = WqT + (size_t)D_ * D_;             // [D_][D_]    2 MB

  prep_w<<<dim3(D_ / 64, D_ / 64, 2), 256, 0, stream>>>(Wq, Wk, WqT, WkT);
  proj_kernel<<<dim3(M_ / 128, D_ / 64), 512, 0, stream>>>(hs, WqT, WkT, bq, bk, K2b, QT);
  attn_kernel<<<dim3(S_ / 256, B_ * H_), 1024, 0, stream>>>(QT, K2b, msk, out);
}